// Round 15
// baseline (213.426 us; speedup 1.0000x reference)
//
#include <hip/hip_runtime.h>
#include <hip/hip_bf16.h>
#include <cstddef>
#include <cstdint>

#define D_MODEL 256
#define N_TOK   16384
#define NHEAD   8
#define HDIM    32
#define LNEIGH  32
#define DFF     2048

typedef short bf16x8 __attribute__((ext_vector_type(8)));
typedef float f32x4  __attribute__((ext_vector_type(4)));

__device__ __forceinline__ float b2f(short s) {
    unsigned u = ((unsigned)(unsigned short)s) << 16;
    return __builtin_bit_cast(float, u);
}

// global -> LDS async copy, 16B per lane; LDS fills base + lane*16.
__device__ __forceinline__ void gload_lds16(const void* g, void* l) {
    auto* gp = reinterpret_cast<const __attribute__((address_space(1))) uint32_t*>(
        reinterpret_cast<uintptr_t>(g));
    auto* lp = reinterpret_cast<__attribute__((address_space(3))) uint32_t*>(
        reinterpret_cast<uintptr_t>(l));
    __builtin_amdgcn_global_load_lds(gp, lp, 16, 0, 0);
}

// ---------------------------------------------------------------------------
// bf16 MFMA GEMM, 128x128 tile, 4 waves, double-buffered K-loop.
// C = A[M,K] @ Bt[N,K]^T. Epilogue: +bias, relu, bf16 out (pitch ldc).
// Used for FFN1 (grid (16,128) = 2048 blocks).
// ---------------------------------------------------------------------------
__global__ __launch_bounds__(256) void gemm_bt(
    const __hip_bfloat16* __restrict__ A, int lda,
    const __hip_bfloat16* __restrict__ Bt, int ldb,
    const float* __restrict__ bias,
    __hip_bfloat16* __restrict__ outb, int ldc,
    int M, int N, int K, int relu)
{
    __shared__ short Asm[2][128 * 32];
    __shared__ short Bsm[2][128 * 32];

    const int tid  = threadIdx.x;
    const int lane = tid & 63;
    const int wid  = tid >> 6;
    const int wr   = wid >> 1;
    const int wc   = wid & 1;
    const int bm   = blockIdx.y * 128;
    const int bn   = blockIdx.x * 128;

    f32x4 acc[4][4] = {};
    const int srow = lane >> 2;
    const int seg  = (lane & 3) * 8;

    auto stage = [&](int buf, int k0) {
        #pragma unroll
        for (int t = 0; t < 2; ++t) {
            int rbase = wid * 32 + t * 16;
            gload_lds16(A  + (size_t)(bm + rbase + srow) * lda + k0 + seg, &Asm[buf][rbase * 32]);
            gload_lds16(Bt + (size_t)(bn + rbase + srow) * ldb + k0 + seg, &Bsm[buf][rbase * 32]);
        }
    };

    const int nk = K >> 5;
    stage(0, 0);
    __syncthreads();

    for (int kk = 0; kk < nk; ++kk) {
        const int cur = kk & 1;
        if (kk + 1 < nk) stage(cur ^ 1, (kk + 1) << 5);

        bf16x8 a[4], b[4];
        #pragma unroll
        for (int i = 0; i < 4; ++i)
            a[i] = *(const bf16x8*)&Asm[cur][(wr * 64 + i * 16 + (lane & 15)) * 32 + (lane >> 4) * 8];
        #pragma unroll
        for (int j = 0; j < 4; ++j)
            b[j] = *(const bf16x8*)&Bsm[cur][(wc * 64 + j * 16 + (lane & 15)) * 32 + (lane >> 4) * 8];
        #pragma unroll
        for (int i = 0; i < 4; ++i)
            #pragma unroll
            for (int j = 0; j < 4; ++j)
                acc[i][j] = __builtin_amdgcn_mfma_f32_16x16x32_bf16(a[i], b[j], acc[i][j], 0, 0, 0);
        __syncthreads();
    }

    #pragma unroll
    for (int i = 0; i < 4; ++i) {
        int rbase = bm + wr * 64 + i * 16 + ((lane >> 4) << 2);
        #pragma unroll
        for (int j = 0; j < 4; ++j) {
            int col = bn + wc * 64 + j * 16 + (lane & 15);
            float bval = bias ? bias[col] : 0.0f;
            #pragma unroll
            for (int r = 0; r < 4; ++r) {
                int row = rbase + r;
                float v = acc[i][j][r] + bval;
                if (relu) v = fmaxf(v, 0.0f);
                outb[(size_t)row * ldc + col] = __float2bfloat16(v);
            }
        }
    }
}

// ---------------------------------------------------------------------------
// Counted-vmcnt LN-GEMM (T4): BM=64 x N=256, 8 waves (2x4), wave = 32x64, BK=64.
// B direct from global into register dbuf (weight is L2-resident, 1 MB).
// A via TRIPLE-buffered LDS (24 KB, XOR-swizzled both sides).
// Per iter: stage A[kk+2], load B[kk+1], MFMA(A[kk],B[kk]), vmcnt(9),
// raw s_barrier -> 9 loads stay in flight ACROSS the barrier (never vmcnt(0)
// in the main loop). Safety: A[kk+1] is older than B[kk], so the compiler's
// pre-MFMA wait on B[kk] retires it per-wave; vmcnt(9)+barrier publishes it
// block-wide; WAR on buf (kk+2)%3 is covered by barrier kk-1.
// Fused bias + residual + LayerNorm epilogue. Grid = M/64 = 256 blocks.
// ---------------------------------------------------------------------------
__global__ __launch_bounds__(512) void gemm_breg_ln(
    const __hip_bfloat16* __restrict__ A, int lda,
    const __hip_bfloat16* __restrict__ Bt, int ldb,
    const float* __restrict__ bias,
    const float* __restrict__ residf,
    const __hip_bfloat16* __restrict__ residb,
    const float* __restrict__ g,
    const float* __restrict__ be,
    float* __restrict__ outf,
    __hip_bfloat16* __restrict__ outb,
    int K)
{
    __shared__ short AsmB[3][64 * 64];       // 24 KB triple buffer
    __shared__ float lnS[8][64], lnS2[8][64];
    __shared__ float rmu[64], rrs[64];

    const int tid  = threadIdx.x;
    const int lane = tid & 63;
    const int wid  = tid >> 6;           // 0..7
    const int wr   = wid >> 2;           // 0..1 (32-row half)
    const int wc   = wid & 3;            // 0..3 (64-col quarter)
    const int bm   = blockIdx.x * 64;
    const int lo   = lane & 15;
    const int hi   = lane >> 4;

    f32x4 acc[2][4] = {};

    // A staging: stripe = 8 rows x 8 chunks (16B), swizzled source chunk
    const int srow8 = lane >> 3;
    const int sc    = lane & 7;
    const int ssw   = ((sc ^ srow8) << 3);

    auto stageA = [&](int buf, int k0) {
        gload_lds16(A + (size_t)(bm + wid * 8 + srow8) * lda + k0 + ssw,
                    &AsmB[buf][(wid * 8) * 64]);
    };

    // B row pointers: lane's 4 fragment rows (C-cols), chunk hi
    const __hip_bfloat16* brow[4];
    #pragma unroll
    for (int j = 0; j < 4; ++j)
        brow[j] = Bt + (size_t)(wc * 64 + j * 16 + lo) * ldb + hi * 8;

    bf16x8 bcur[4][2], bnext[4][2];
    const int nk = K >> 6;

    // prologue: A[0], A[1] staged; B[0] in regs; wait A[0] (9 newer in flight)
    stageA(0, 0);
    stageA(1, 64);
    #pragma unroll
    for (int j = 0; j < 4; ++j)
        #pragma unroll
        for (int ks = 0; ks < 2; ++ks)
            bcur[j][ks] = *(const bf16x8*)(brow[j] + ks * 32);
    asm volatile("s_waitcnt vmcnt(9)" ::: "memory");
    __builtin_amdgcn_s_barrier();
    __builtin_amdgcn_sched_barrier(0);

    for (int kk = 0; kk < nk; ++kk) {
        const int cur = kk % 3;
        if (kk + 2 < nk) stageA((kk + 2) % 3, (kk + 2) << 6);
        if (kk + 1 < nk) {
            #pragma unroll
            for (int j = 0; j < 4; ++j)
                #pragma unroll
                for (int ks = 0; ks < 2; ++ks)
                    bnext[j][ks] = *(const bf16x8*)(brow[j] + (size_t)(kk + 1) * 64 + ks * 32);
        }

        const short* Ab = &AsmB[cur][0];
        #pragma unroll
        for (int ks = 0; ks < 2; ++ks) {
            const int csw = ((ks * 4 + hi) ^ (lo & 7)) << 3;   // swizzled read chunk
            bf16x8 a0 = *(const bf16x8*)&Ab[(wr * 32 + lo) * 64 + csw];
            bf16x8 a1 = *(const bf16x8*)&Ab[(wr * 32 + 16 + lo) * 64 + csw];
            acc[0][0] = __builtin_amdgcn_mfma_f32_16x16x32_bf16(a0, bcur[0][ks], acc[0][0], 0, 0, 0);
            acc[0][1] = __builtin_amdgcn_mfma_f32_16x16x32_bf16(a0, bcur[1][ks], acc[0][1], 0, 0, 0);
            acc[0][2] = __builtin_amdgcn_mfma_f32_16x16x32_bf16(a0, bcur[2][ks], acc[0][2], 0, 0, 0);
            acc[0][3] = __builtin_amdgcn_mfma_f32_16x16x32_bf16(a0, bcur[3][ks], acc[0][3], 0, 0, 0);
            acc[1][0] = __builtin_amdgcn_mfma_f32_16x16x32_bf16(a1, bcur[0][ks], acc[1][0], 0, 0, 0);
            acc[1][1] = __builtin_amdgcn_mfma_f32_16x16x32_bf16(a1, bcur[1][ks], acc[1][1], 0, 0, 0);
            acc[1][2] = __builtin_amdgcn_mfma_f32_16x16x32_bf16(a1, bcur[2][ks], acc[1][2], 0, 0, 0);
            acc[1][3] = __builtin_amdgcn_mfma_f32_16x16x32_bf16(a1, bcur[3][ks], acc[1][3], 0, 0, 0);
        }
        #pragma unroll
        for (int j = 0; j < 4; ++j)
            #pragma unroll
            for (int ks = 0; ks < 2; ++ks)
                bcur[j][ks] = bnext[j][ks];

        if (kk + 2 < nk)      asm volatile("s_waitcnt vmcnt(9)" ::: "memory");
        else if (kk + 1 < nk) asm volatile("s_waitcnt vmcnt(8)" ::: "memory");
        else                  asm volatile("s_waitcnt vmcnt(0)" ::: "memory");
        __builtin_amdgcn_s_barrier();
        __builtin_amdgcn_sched_barrier(0);
    }

    // epilogue: bias + resid, per-row mean/var partials over this wave's 64 cols
    float ps[2][4] = {}, ps2[2][4] = {};
    #pragma unroll
    for (int j = 0; j < 4; ++j) {
        int col = wc * 64 + j * 16 + lo;
        float bval = bias ? bias[col] : 0.0f;
        #pragma unroll
        for (int i = 0; i < 2; ++i) {
            #pragma unroll
            for (int r = 0; r < 4; ++r) {
                int row = bm + wr * 32 + i * 16 + hi * 4 + r;
                float v = acc[i][j][r] + bval;
                size_t o = (size_t)row * 256 + col;
                if (residf) v += residf[o];
                if (residb) v += __bfloat162float(residb[o]);
                acc[i][j][r] = v;
                ps[i][r]  += v;
                ps2[i][r] += v * v;
            }
        }
    }
    #pragma unroll
    for (int i = 0; i < 2; ++i)
        #pragma unroll
        for (int r = 0; r < 4; ++r) {
            #pragma unroll
            for (int m = 1; m < 16; m <<= 1) {
                ps[i][r]  += __shfl_xor(ps[i][r],  m);
                ps2[i][r] += __shfl_xor(ps2[i][r], m);
            }
        }
    if (lo == 0) {
        #pragma unroll
        for (int i = 0; i < 2; ++i)
            #pragma unroll
            for (int r = 0; r < 4; ++r) {
                int rl = wr * 32 + i * 16 + hi * 4 + r;
                lnS[wid][rl]  = ps[i][r];
                lnS2[wid][rl] = ps2[i][r];
            }
    }
    __syncthreads();
    if (tid < 64) {
        int base = (tid >> 5) * 4;       // the 4 waves (wc=0..3) sharing this row
        float s  = lnS[base][tid] + lnS[base + 1][tid] + lnS[base + 2][tid] + lnS[base + 3][tid];
        float s2 = lnS2[base][tid] + lnS2[base + 1][tid] + lnS2[base + 2][tid] + lnS2[base + 3][tid];
        float mu  = s * (1.0f / 256.0f);
        float var = s2 * (1.0f / 256.0f) - mu * mu;
        rmu[tid] = mu;
        rrs[tid] = rsqrtf(var + 1e-5f);
    }
    __syncthreads();

    #pragma unroll
    for (int j = 0; j < 4; ++j) {
        int col = wc * 64 + j * 16 + lo;
        float gg = g[col], bb = be[col];
        #pragma unroll
        for (int i = 0; i < 2; ++i) {
            #pragma unroll
            for (int r = 0; r < 4; ++r) {
                int rl = wr * 32 + i * 16 + hi * 4 + r;
                float v = (acc[i][j][r] - rmu[rl]) * rrs[rl] * gg + bb;
                size_t o = (size_t)(bm + rl) * 256 + col;
                if (outf) outf[o] = v;
                if (outb) outb[o] = __float2bfloat16(v);
            }
        }
    }
}

// ---------------------------------------------------------------------------
// QKV GEMM: C = src_bf @ WqkvT^T (N=768, K=256), split epilogue:
// cols [0,256)  -> qf  f32 [N_TOK][256]   (scale pre-folded)
// cols [256,768)-> kvb bf16 [N_TOK][512]  (k|v, gather-friendly, L2-resident)
// ---------------------------------------------------------------------------
__global__ __launch_bounds__(256) void gemm_qkv(
    const __hip_bfloat16* __restrict__ A,
    const __hip_bfloat16* __restrict__ Bt,
    const float* __restrict__ bias,
    float* __restrict__ qf,
    __hip_bfloat16* __restrict__ kvb)
{
    __shared__ short Asm[2][128 * 32];
    __shared__ short Bsm[2][128 * 32];

    const int tid  = threadIdx.x;
    const int lane = tid & 63;
    const int wid  = tid >> 6;
    const int wr   = wid >> 1;
    const int wc   = wid & 1;
    const int bm   = blockIdx.y * 128;
    const int bn   = blockIdx.x * 128;

    f32x4 acc[4][4] = {};
    const int srow = lane >> 2;
    const int seg  = (lane & 3) * 8;

    auto stage = [&](int buf, int k0) {
        #pragma unroll
        for (int t = 0; t < 2; ++t) {
            int rbase = wid * 32 + t * 16;
            gload_lds16(A  + (size_t)(bm + rbase + srow) * 256 + k0 + seg, &Asm[buf][rbase * 32]);
            gload_lds16(Bt + (size_t)(bn + rbase + srow) * 256 + k0 + seg, &Bsm[buf][rbase * 32]);
        }
    };

    stage(0, 0);
    __syncthreads();
    for (int kk = 0; kk < 8; ++kk) {
        const int cur = kk & 1;
        if (kk + 1 < 8) stage(cur ^ 1, (kk + 1) << 5);
        bf16x8 a[4], b[4];
        #pragma unroll
        for (int i = 0; i < 4; ++i)
            a[i] = *(const bf16x8*)&Asm[cur][(wr * 64 + i * 16 + (lane & 15)) * 32 + (lane >> 4) * 8];
        #pragma unroll
        for (int j = 0; j < 4; ++j)
            b[j] = *(const bf16x8*)&Bsm[cur][(wc * 64 + j * 16 + (lane & 15)) * 32 + (lane >> 4) * 8];
        #pragma unroll
        for (int i = 0; i < 4; ++i)
            #pragma unroll
            for (int j = 0; j < 4; ++j)
                acc[i][j] = __builtin_amdgcn_mfma_f32_16x16x32_bf16(a[i], b[j], acc[i][j], 0, 0, 0);
        __syncthreads();
    }

    const bool isq = (bn < 256);
    #pragma unroll
    for (int i = 0; i < 4; ++i) {
        int rbase = bm + wr * 64 + i * 16 + ((lane >> 4) << 2);
        #pragma unroll
        for (int j = 0; j < 4; ++j) {
            int col = bn + wc * 64 + j * 16 + (lane & 15);
            float bval = bias[col];
            #pragma unroll
            for (int r = 0; r < 4; ++r) {
                int row = rbase + r;
                float v = acc[i][j][r] + bval;
                if (isq) qf[(size_t)row * 256 + col] = v;
                else     kvb[(size_t)row * 512 + (col - 256)] = __float2bfloat16(v);
            }
        }
    }
}

// ---------------------------------------------------------------------------
__global__ __launch_bounds__(256) void cvt_f2b(
    const float* __restrict__ x, __hip_bfloat16* __restrict__ y, int n)
{
    int i = (blockIdx.x * 256 + threadIdx.x) * 4;
    if (i >= n) return;
    float4 v = *(const float4*)(x + i);
    y[i + 0] = __float2bfloat16(v.x);
    y[i + 1] = __float2bfloat16(v.y);
    y[i + 2] = __float2bfloat16(v.z);
    y[i + 3] = __float2bfloat16(v.w);
}

// Tiled transpose: W[K][N] fp32 -> Wt[N][K] bf16, output pitch ldo.
__global__ __launch_bounds__(256) void cvt_wt_tiled(
    const float* __restrict__ W, __hip_bfloat16* __restrict__ Wt,
    int K, int N, int ldo, float scale)
{
    __shared__ float t[32][33];
    const int n0 = blockIdx.x * 32;
    const int k0 = blockIdx.y * 32;
    const int tx = threadIdx.x & 31;
    const int ty = threadIdx.x >> 5;
    #pragma unroll
    for (int i = 0; i < 32; i += 8)
        t[ty + i][tx] = W[(size_t)(k0 + ty + i) * N + n0 + tx];
    __syncthreads();
    #pragma unroll
    for (int i = 0; i < 32; i += 8)
        Wt[(size_t)(n0 + ty + i) * ldo + k0 + tx] = __float2bfloat16(t[tx][ty + i] * scale);
}

__global__ __launch_bounds__(256) void cvt_w3_tiled(
    const float* __restrict__ Wa, const float* __restrict__ Wb,
    const float* __restrict__ Wc, __hip_bfloat16* __restrict__ Wt,
    float scale_a)
{
    __shared__ float t[32][33];
    const int n0 = blockIdx.x * 32;
    const int k0 = blockIdx.y * 32;
    const float* W = (n0 < 256) ? Wa : (n0 < 512 ? Wb : Wc);
    const float sc = (n0 < 256) ? scale_a : 1.0f;
    const int ncol = n0 & 255;
    const int tx = threadIdx.x & 31;
    const int ty = threadIdx.x >> 5;
    #pragma unroll
    for (int i = 0; i < 32; i += 8)
        t[ty + i][tx] = W[(size_t)(k0 + ty + i) * 256 + ncol + tx];
    __syncthreads();
    #pragma unroll
    for (int i = 0; i < 32; i += 8)
        Wt[(size_t)(n0 + ty + i) * 256 + k0 + tx] = __float2bfloat16(t[tx][ty + i] * sc);
}

// biases + key_start prefix sums (batch offsets)
__global__ __launch_bounds__(768) void make_bqkv(
    const float* __restrict__ bq, const float* __restrict__ bk,
    const float* __restrict__ bv, const int* __restrict__ kbc, int nb,
    float* __restrict__ o, int* __restrict__ ks, float qs)
{
    int i = threadIdx.x;
    if (i < 256)      o[i] = bq[i] * qs;
    else if (i < 512) o[i] = bk[i - 256];
    else              o[i] = bv[i - 512];
    if (i < nb) {
        int acc = 0;
        for (int j = 0; j < i; ++j) acc += kbc[j];
        ks[i] = acc;
    }
}

// ---------------------------------------------------------------------------
// Gathered local attention: ONE WAVE per query, fully coalesced row gathers.
// (unchanged from round 9 — 210->169 us win)
// ---------------------------------------------------------------------------
__global__ __launch_bounds__(256) void attn_wave(
    const float* __restrict__ qf,
    const __hip_bfloat16* __restrict__ kvb,
    const int* __restrict__ index_pair,
    const int* __restrict__ ipb,
    const int* __restrict__ key_start,
    __hip_bfloat16* __restrict__ out)
{
    const int w    = threadIdx.x >> 6;
    const int lane = threadIdx.x & 63;
    const int bid  = blockIdx.x;
    const int n  = (bid & 7) * 2048 + (bid >> 3) * 4 + w;
    const int c  = lane & 31;      // dim chunk: dims [c*8, c*8+8)
    const int pp = lane >> 5;      // row parity

    int raw = index_pair[(size_t)n * LNEIGH + c];
    int ks  = key_start[ipb[n]];
    int gi0 = (raw >= 0) ? raw + ks : -1;

    const float* qp = qf + (size_t)n * 256 + c * 8;
    float4 q0 = *(const float4*)(qp);
    float4 q1 = *(const float4*)(qp + 4);

    int gi[16];
    #pragma unroll
    for (int i = 0; i < 16; ++i) gi[i] = __shfl(gi0, 2 * i + pp);

    bf16x8 kr[16];
    #pragma unroll
    for (int i = 0; i < 16; ++i) {
        int g = gi[i] < 0 ? 0 : gi[i];
        kr[i] = *(const bf16x8*)(kvb + (size_t)g * 512 + c * 8);
    }

    float s[16];
    #pragma unroll
    for (int i = 0; i < 16; ++i) {
        float t = q0.x * b2f(kr[i][0]) + q0.y * b2f(kr[i][1])
                + q0.z * b2f(kr[i][2]) + q0.w * b2f(kr[i][3])
                + q1.x * b2f(kr[i][4]) + q1.y * b2f(kr[i][5])
                + q1.z * b2f(kr[i][6]) + q1.w * b2f(kr[i][7]);
        t += __shfl_xor(t, 1);
        t += __shfl_xor(t, 2);
        s[i] = (gi[i] < 0) ? -1e9f : t;
    }

    bf16x8 vr[16];
    #pragma unroll
    for (int i = 0; i < 16; ++i) {
        int g = gi[i] < 0 ? 0 : gi[i];
        vr[i] = *(const bf16x8*)(kvb + (size_t)g * 512 + 256 + c * 8);
    }

    float m = s[0];
    #pragma unroll
    for (int i = 1; i < 16; ++i) m = fmaxf(m, s[i]);
    m = fmaxf(m, __shfl_xor(m, 32));
    float tot = 0.0f;
    #pragma unroll
    for (int i = 0; i < 16; ++i) { s[i] = __expf(s[i] - m); tot += s[i]; }
    tot += __shfl_xor(tot, 32);
    const float inv = 1.0f / tot;

    float a[8] = {};
    #pragma unroll
    for (int i = 0; i < 16; ++i) {
        float wt = s[i] * inv;
        #pragma unroll
        for (int j = 0; j < 8; ++j) a[j] += wt * b2f(vr[i][j]);
    }
    #pragma unroll
    for (int j = 0; j < 8; ++j) a[j] += __shfl_xor(a[j], 32);

    if (pp == 0) {
        bf16x8 ov;
        #pragma unroll
        for (int j = 0; j < 8; ++j)
            ov[j] = __builtin_bit_cast(short, __float2bfloat16(a[j]));
        *(bf16x8*)((short*)out + (size_t)n * 256 + c * 8) = ov;
    }
}

// ---------------------------------------------------------------------------
extern "C" void kernel_launch(void* const* d_in, const int* in_sizes, int n_in,
                              void* d_out, int out_size, void* d_ws, size_t ws_size,
                              hipStream_t stream)
{
    const float* src = (const float*)d_in[0];
    const int*   index_pair = (const int*)d_in[1];
    const int*   kbc = (const int*)d_in[3];
    const int*   ipb = (const int*)d_in[4];
    const float* Wq = (const float*)d_in[5];
    const float* bq = (const float*)d_in[6];
    const float* Wk = (const float*)d_in[7];
    const float* bk = (const float*)d_in[8];
    const float* Wv = (const float*)d_in[9];
    const float* bv = (const float*)d_in[10];
    const float* Wo = (const float*)d_in[11];
    const float* bo = (const float*)d_in[12];
    const float* W1 = (const float*)d_in[13];
    const float* b1 = (const float*)d_in[14];
    const float* W2 = (const float*)d_in[15];
    const float* b2 = (const float*)d_in[16];
    const float* g1 = (const float*)d_in[17];
    const float* be1 = (const float*)d_in[18];
    const float* g2 = (const float*)d_in[19];
    const float* be2 = (const float*)d_in[20];
    float* out = (float*)d_out;
    const int nb = in_sizes[3];   // number of batches

    char* ws = (char*)d_ws;
    // Attention-phase buffers die before FFN1; hc (64 MB at offset 0) aliases.
    const size_t O_SRCBF = 0;                        //  8.39 MB bf16 src
    const size_t O_QF    = 8388608;                  // 16.78 MB f32 q
    const size_t O_KVB   = 25165824;                 // 16.78 MB bf16 k|v
    const size_t O_ATTN  = 41943040;                 //  8.39 MB bf16 attn out
    const size_t O_HC    = 0;                        // 64 MB alias (FFN hidden)
    const size_t O_XBF   = 67108864;                 //  8.39 MB bf16 x (LN1 out)
    const size_t O_WQKV  = 75497472;
    const size_t O_WO    = O_WQKV + 768 * 256 * 2;
    const size_t O_W1    = O_WO + 256 * 256 * 2;
    const size_t O_W2    = O_W1 + (size_t)DFF * 256 * 2;
    const size_t O_BQKV  = O_W2 + (size_t)DFF * 256 * 2;
    const size_t O_KS    = O_BQKV + 768 * 4;

    __hip_bfloat16* src_bf  = (__hip_bfloat16*)(ws + O_SRCBF);
    float*          qf      = (float*)(ws + O_QF);
    __hip_bfloat16* kvb     = (__hip_bfloat16*)(ws + O_KVB);
    __hip_bfloat16* attn_bf = (__hip_bfloat16*)(ws + O_ATTN);
    __hip_bfloat16* hc      = (__hip_bfloat16*)(ws + O_HC);
    __hip_bfloat16* x_bf    = (__hip_bfloat16*)(ws + O_XBF);
    __hip_bfloat16* WqkvT   = (__hip_bfloat16*)(ws + O_WQKV);
    __hip_bfloat16* WoT     = (__hip_bfloat16*)(ws + O_WO);
    __hip_bfloat16* W1T     = (__hip_bfloat16*)(ws + O_W1);
    __hip_bfloat16* W2T     = (__hip_bfloat16*)(ws + O_W2);
    float*          bqkv    = (float*)(ws + O_BQKV);
    int*            ksbuf   = (int*)(ws + O_KS);

    const dim3 blk(256);
    const float qscale = 0.17677669529663687f;

    // --- conversions ---
    cvt_f2b<<<N_TOK * D_MODEL / 4 / 256, blk, 0, stream>>>(src, src_bf, N_TOK * D_MODEL);
    cvt_w3_tiled<<<dim3(24, 8), blk, 0, stream>>>(Wq, Wk, Wv, WqkvT, qscale);
    cvt_wt_tiled<<<dim3(8, 8),  blk, 0, stream>>>(Wo, WoT, 256, 256, 256, 1.0f);
    cvt_wt_tiled<<<dim3(64, 8), blk, 0, stream>>>(W1, W1T, 256, DFF, 256, 1.0f);
    cvt_wt_tiled<<<dim3(8, 64), blk, 0, stream>>>(W2, W2T, DFF, 256, DFF, 1.0f);
    make_bqkv<<<1, 768, 0, stream>>>(bq, bk, bv, kbc, nb, bqkv, ksbuf, qscale);

    // --- fused QKV projection: q -> f32 qf, k|v -> bf16 kvb ---
    gemm_qkv<<<dim3(6, 128), blk, 0, stream>>>(src_bf, WqkvT, bqkv, qf, kvb);

    // --- gathered attention (wave per query, coalesced row gathers) ---
    attn_wave<<<dim3(N_TOK / 4), blk, 0, stream>>>(qf, kvb, index_pair, ipb, ksbuf, attn_bf);

    // --- Wo + residual(src) + LN1 fused -> x_bf (counted-vmcnt LN-GEMM) ---
    gemm_breg_ln<<<dim3(N_TOK / 64), dim3(512), 0, stream>>>(
        attn_bf, 256, WoT, 256, bo, src, nullptr, g1, be1,
        nullptr, x_bf, 256);

    // --- FFN1 (N=2048, relu) -> hc ---
    gemm_bt<<<dim3(16, 128), blk, 0, stream>>>(
        x_bf, 256, W1T, 256, b1, hc, DFF, N_TOK, DFF, 256, 1);

    // --- FFN2 + residual(x_bf) + LN2 fused -> out (counted-vmcnt LN-GEMM) ---
    gemm_breg_ln<<<dim3(N_TOK / 64), dim3(512), 0, stream>>>(
        hc, DFF, W2T, DFF, b2, nullptr, x_bf, g2, be2,
        out, nullptr, DFF);
}

// Round 16
// 152.625 us; speedup vs baseline: 1.3984x; 1.3984x over previous
//
#include <hip/hip_runtime.h>
#include <hip/hip_bf16.h>
#include <cstddef>
#include <cstdint>

#define D_MODEL 256
#define N_TOK   16384
#define NHEAD   8
#define HDIM    32
#define LNEIGH  32
#define DFF     2048

// dynamic LDS for gemm_bk64_ln32: A dbuf 8K + B dbuf 64K (LN scratch aliases A)
#define SMEM_LN32 (8192 + 65536)   // 73728 B -> 2 blocks/CU

typedef short bf16x8 __attribute__((ext_vector_type(8)));
typedef float f32x4  __attribute__((ext_vector_type(4)));

__device__ __forceinline__ float b2f(short s) {
    unsigned u = ((unsigned)(unsigned short)s) << 16;
    return __builtin_bit_cast(float, u);
}

// global -> LDS async copy, 16B per lane; LDS fills base + lane*16.
__device__ __forceinline__ void gload_lds16(const void* g, void* l) {
    auto* gp = reinterpret_cast<const __attribute__((address_space(1))) uint32_t*>(
        reinterpret_cast<uintptr_t>(g));
    auto* lp = reinterpret_cast<__attribute__((address_space(3))) uint32_t*>(
        reinterpret_cast<uintptr_t>(l));
    __builtin_amdgcn_global_load_lds(gp, lp, 16, 0, 0);
}

// ---------------------------------------------------------------------------
// bf16 MFMA GEMM, 128x128 tile, 4 waves, double-buffered K-loop.
// C = A[M,K] @ Bt[N,K]^T. Epilogue: +bias, relu, bf16 out (pitch ldc).
// Used for FFN1 (grid (16,128) = 2048 blocks).
// ---------------------------------------------------------------------------
__global__ __launch_bounds__(256) void gemm_bt(
    const __hip_bfloat16* __restrict__ A, int lda,
    const __hip_bfloat16* __restrict__ Bt, int ldb,
    const float* __restrict__ bias,
    __hip_bfloat16* __restrict__ outb, int ldc,
    int M, int N, int K, int relu)
{
    __shared__ short Asm[2][128 * 32];
    __shared__ short Bsm[2][128 * 32];

    const int tid  = threadIdx.x;
    const int lane = tid & 63;
    const int wid  = tid >> 6;
    const int wr   = wid >> 1;
    const int wc   = wid & 1;
    const int bm   = blockIdx.y * 128;
    const int bn   = blockIdx.x * 128;

    f32x4 acc[4][4] = {};
    const int srow = lane >> 2;
    const int seg  = (lane & 3) * 8;

    auto stage = [&](int buf, int k0) {
        #pragma unroll
        for (int t = 0; t < 2; ++t) {
            int rbase = wid * 32 + t * 16;
            gload_lds16(A  + (size_t)(bm + rbase + srow) * lda + k0 + seg, &Asm[buf][rbase * 32]);
            gload_lds16(Bt + (size_t)(bn + rbase + srow) * ldb + k0 + seg, &Bsm[buf][rbase * 32]);
        }
    };

    const int nk = K >> 5;
    stage(0, 0);
    __syncthreads();

    for (int kk = 0; kk < nk; ++kk) {
        const int cur = kk & 1;
        if (kk + 1 < nk) stage(cur ^ 1, (kk + 1) << 5);

        bf16x8 a[4], b[4];
        #pragma unroll
        for (int i = 0; i < 4; ++i)
            a[i] = *(const bf16x8*)&Asm[cur][(wr * 64 + i * 16 + (lane & 15)) * 32 + (lane >> 4) * 8];
        #pragma unroll
        for (int j = 0; j < 4; ++j)
            b[j] = *(const bf16x8*)&Bsm[cur][(wc * 64 + j * 16 + (lane & 15)) * 32 + (lane >> 4) * 8];
        #pragma unroll
        for (int i = 0; i < 4; ++i)
            #pragma unroll
            for (int j = 0; j < 4; ++j)
                acc[i][j] = __builtin_amdgcn_mfma_f32_16x16x32_bf16(a[i], b[j], acc[i][j], 0, 0, 0);
        __syncthreads();
    }

    #pragma unroll
    for (int i = 0; i < 4; ++i) {
        int rbase = bm + wr * 64 + i * 16 + ((lane >> 4) << 2);
        #pragma unroll
        for (int j = 0; j < 4; ++j) {
            int col = bn + wc * 64 + j * 16 + (lane & 15);
            float bval = bias ? bias[col] : 0.0f;
            #pragma unroll
            for (int r = 0; r < 4; ++r) {
                int row = rbase + r;
                float v = acc[i][j][r] + bval;
                if (relu) v = fmaxf(v, 0.0f);
                outb[(size_t)row * ldc + col] = __float2bfloat16(v);
            }
        }
    }
}

// ---------------------------------------------------------------------------
// BK=64 LN-GEMM, BM=32: N=256, 8 waves (2x4), wave = 16x64.
// Grid = M/32 = 512 blocks; dynamic LDS 72 KB -> 2 blocks/CU, 16 waves/CU:
// the second resident block covers the per-barrier vmcnt drain (round-14's
// 1-block/CU was the binding constraint). Staging XOR-swizzled both sides
// (chunk ^= row&7) -> conflict-free b128 reads (round-14 verified: 0 conflicts).
// LN scratch ALIASES the dead A buffer after the K-loop (keeps LDS at 72 KB).
// Fused bias + residual + LayerNorm epilogue.
// ---------------------------------------------------------------------------
__global__ __launch_bounds__(512) void gemm_bk64_ln32(
    const __hip_bfloat16* __restrict__ A, int lda,
    const __hip_bfloat16* __restrict__ Bt, int ldb,
    const float* __restrict__ bias,
    const float* __restrict__ residf,
    const __hip_bfloat16* __restrict__ residb,
    const float* __restrict__ g,
    const float* __restrict__ be,
    float* __restrict__ outf,
    __hip_bfloat16* __restrict__ outb,
    int K)
{
    extern __shared__ char smem[];
    short* AsmB = (short*)smem;                      // [2][32*64]   8 KB
    short* BsmB = (short*)(smem + 8192);             // [2][256*64]  64 KB
    // LN scratch aliases the A region (dead after the K-loop):
    float* lnS  = (float*)smem;                      // [8][32]  1 KB
    float* lnS2 = (float*)(smem + 1024);             // [8][32]  1 KB
    float* rmu  = (float*)(smem + 2048);             // [32]
    float* rrs  = (float*)(smem + 2176);             // [32]

    const int tid  = threadIdx.x;
    const int lane = tid & 63;
    const int wid  = tid >> 6;           // 0..7
    const int wr   = wid >> 2;           // 0..1 (16-row half)
    const int wc   = wid & 3;            // 0..3 (64-col quarter)
    const int bm   = blockIdx.x * 32;
    const int lo   = lane & 15;
    const int hi   = lane >> 4;

    f32x4 acc[4] = {};

    // staging lane decomposition: stripe = 8 rows x 8 chunks (16B each)
    const int srow8 = lane >> 3;         // row within stripe
    const int sc    = lane & 7;          // chunk slot
    const int ssw   = ((sc ^ srow8) << 3);   // swizzled source chunk (elems)

    auto stage = [&](int buf, int k0) {
        // A: 32 rows = 4 stripes (waves 0..3)
        if (wid < 4)
            gload_lds16(A + (size_t)(bm + wid * 8 + srow8) * lda + k0 + ssw,
                        AsmB + buf * 2048 + (wid * 8) * 64);
        // B: 256 rows = 32 stripes, 4 per wave
        #pragma unroll
        for (int t = 0; t < 4; ++t) {
            int rb = wid * 32 + t * 8;
            gload_lds16(Bt + (size_t)(rb + srow8) * ldb + k0 + ssw,
                        BsmB + buf * 16384 + rb * 64);
        }
    };

    const int nk = K >> 6;
    stage(0, 0);
    __syncthreads();

    for (int kk = 0; kk < nk; ++kk) {
        const int cur = kk & 1;
        if (kk + 1 < nk) stage(cur ^ 1, (kk + 1) << 6);

        const short* Ab = AsmB + cur * 2048;
        const short* Bb = BsmB + cur * 16384;
        #pragma unroll
        for (int ks = 0; ks < 2; ++ks) {
            const int csw = ((ks * 4 + hi) ^ (lo & 7)) << 3;  // swizzled read chunk
            bf16x8 a = *(const bf16x8*)&Ab[(wr * 16 + lo) * 64 + csw];
            bf16x8 b[4];
            #pragma unroll
            for (int j = 0; j < 4; ++j)
                b[j] = *(const bf16x8*)&Bb[(wc * 64 + j * 16 + lo) * 64 + csw];
            #pragma unroll
            for (int j = 0; j < 4; ++j)
                acc[j] = __builtin_amdgcn_mfma_f32_16x16x32_bf16(a, b[j], acc[j], 0, 0, 0);
        }
        __syncthreads();
    }

    // epilogue: bias + resid, per-row mean/var partials over this wave's 64 cols
    float ps[4] = {}, ps2[4] = {};
    #pragma unroll
    for (int j = 0; j < 4; ++j) {
        int col = wc * 64 + j * 16 + lo;
        float bval = bias ? bias[col] : 0.0f;
        #pragma unroll
        for (int r = 0; r < 4; ++r) {
            int row = bm + wr * 16 + hi * 4 + r;
            float v = acc[j][r] + bval;
            size_t o = (size_t)row * 256 + col;
            if (residf) v += residf[o];
            if (residb) v += __bfloat162float(residb[o]);
            acc[j][r] = v;
            ps[r]  += v;
            ps2[r] += v * v;
        }
    }
    #pragma unroll
    for (int r = 0; r < 4; ++r) {
        #pragma unroll
        for (int m = 1; m < 16; m <<= 1) {
            ps[r]  += __shfl_xor(ps[r],  m);
            ps2[r] += __shfl_xor(ps2[r], m);
        }
    }
    // alias region write is safe: last K-loop __syncthreads ordered all reads
    if (lo == 0) {
        #pragma unroll
        for (int r = 0; r < 4; ++r) {
            int rl = wr * 16 + hi * 4 + r;
            lnS[wid * 32 + rl]  = ps[r];
            lnS2[wid * 32 + rl] = ps2[r];
        }
    }
    __syncthreads();
    if (tid < 32) {
        int base = (tid >> 4) * 4;       // the 4 waves (wc=0..3) sharing this row
        float s  = lnS[base * 32 + tid] + lnS[(base + 1) * 32 + tid]
                 + lnS[(base + 2) * 32 + tid] + lnS[(base + 3) * 32 + tid];
        float s2 = lnS2[base * 32 + tid] + lnS2[(base + 1) * 32 + tid]
                 + lnS2[(base + 2) * 32 + tid] + lnS2[(base + 3) * 32 + tid];
        float mu  = s * (1.0f / 256.0f);
        float var = s2 * (1.0f / 256.0f) - mu * mu;
        rmu[tid] = mu;
        rrs[tid] = rsqrtf(var + 1e-5f);
    }
    __syncthreads();

    #pragma unroll
    for (int j = 0; j < 4; ++j) {
        int col = wc * 64 + j * 16 + lo;
        float gg = g[col], bb = be[col];
        #pragma unroll
        for (int r = 0; r < 4; ++r) {
            int rl = wr * 16 + hi * 4 + r;
            float v = (acc[j][r] - rmu[rl]) * rrs[rl] * gg + bb;
            size_t o = (size_t)(bm + rl) * 256 + col;
            if (outf) outf[o] = v;
            if (outb) outb[o] = __float2bfloat16(v);
        }
    }
}

// ---------------------------------------------------------------------------
// QKV GEMM: C = src_bf @ WqkvT^T (N=768, K=256), split epilogue:
// cols [0,256)  -> qf  f32 [N_TOK][256]   (scale pre-folded)
// cols [256,768)-> kvb bf16 [N_TOK][512]  (k|v, gather-friendly, L2-resident)
// ---------------------------------------------------------------------------
__global__ __launch_bounds__(256) void gemm_qkv(
    const __hip_bfloat16* __restrict__ A,
    const __hip_bfloat16* __restrict__ Bt,
    const float* __restrict__ bias,
    float* __restrict__ qf,
    __hip_bfloat16* __restrict__ kvb)
{
    __shared__ short Asm[2][128 * 32];
    __shared__ short Bsm[2][128 * 32];

    const int tid  = threadIdx.x;
    const int lane = tid & 63;
    const int wid  = tid >> 6;
    const int wr   = wid >> 1;
    const int wc   = wid & 1;
    const int bm   = blockIdx.y * 128;
    const int bn   = blockIdx.x * 128;

    f32x4 acc[4][4] = {};
    const int srow = lane >> 2;
    const int seg  = (lane & 3) * 8;

    auto stage = [&](int buf, int k0) {
        #pragma unroll
        for (int t = 0; t < 2; ++t) {
            int rbase = wid * 32 + t * 16;
            gload_lds16(A  + (size_t)(bm + rbase + srow) * 256 + k0 + seg, &Asm[buf][rbase * 32]);
            gload_lds16(Bt + (size_t)(bn + rbase + srow) * 256 + k0 + seg, &Bsm[buf][rbase * 32]);
        }
    };

    stage(0, 0);
    __syncthreads();
    for (int kk = 0; kk < 8; ++kk) {
        const int cur = kk & 1;
        if (kk + 1 < 8) stage(cur ^ 1, (kk + 1) << 5);
        bf16x8 a[4], b[4];
        #pragma unroll
        for (int i = 0; i < 4; ++i)
            a[i] = *(const bf16x8*)&Asm[cur][(wr * 64 + i * 16 + (lane & 15)) * 32 + (lane >> 4) * 8];
        #pragma unroll
        for (int j = 0; j < 4; ++j)
            b[j] = *(const bf16x8*)&Bsm[cur][(wc * 64 + j * 16 + (lane & 15)) * 32 + (lane >> 4) * 8];
        #pragma unroll
        for (int i = 0; i < 4; ++i)
            #pragma unroll
            for (int j = 0; j < 4; ++j)
                acc[i][j] = __builtin_amdgcn_mfma_f32_16x16x32_bf16(a[i], b[j], acc[i][j], 0, 0, 0);
        __syncthreads();
    }

    const bool isq = (bn < 256);
    #pragma unroll
    for (int i = 0; i < 4; ++i) {
        int rbase = bm + wr * 64 + i * 16 + ((lane >> 4) << 2);
        #pragma unroll
        for (int j = 0; j < 4; ++j) {
            int col = bn + wc * 64 + j * 16 + (lane & 15);
            float bval = bias[col];
            #pragma unroll
            for (int r = 0; r < 4; ++r) {
                int row = rbase + r;
                float v = acc[i][j][r] + bval;
                if (isq) qf[(size_t)row * 256 + col] = v;
                else     kvb[(size_t)row * 512 + (col - 256)] = __float2bfloat16(v);
            }
        }
    }
}

// ---------------------------------------------------------------------------
__global__ __launch_bounds__(256) void cvt_f2b(
    const float* __restrict__ x, __hip_bfloat16* __restrict__ y, int n)
{
    int i = (blockIdx.x * 256 + threadIdx.x) * 4;
    if (i >= n) return;
    float4 v = *(const float4*)(x + i);
    y[i + 0] = __float2bfloat16(v.x);
    y[i + 1] = __float2bfloat16(v.y);
    y[i + 2] = __float2bfloat16(v.z);
    y[i + 3] = __float2bfloat16(v.w);
}

// Tiled transpose: W[K][N] fp32 -> Wt[N][K] bf16, output pitch ldo.
__global__ __launch_bounds__(256) void cvt_wt_tiled(
    const float* __restrict__ W, __hip_bfloat16* __restrict__ Wt,
    int K, int N, int ldo, float scale)
{
    __shared__ float t[32][33];
    const int n0 = blockIdx.x * 32;
    const int k0 = blockIdx.y * 32;
    const int tx = threadIdx.x & 31;
    const int ty = threadIdx.x >> 5;
    #pragma unroll
    for (int i = 0; i < 32; i += 8)
        t[ty + i][tx] = W[(size_t)(k0 + ty + i) * N + n0 + tx];
    __syncthreads();
    #pragma unroll
    for (int i = 0; i < 32; i += 8)
        Wt[(size_t)(n0 + ty + i) * ldo + k0 + tx] = __float2bfloat16(t[tx][ty + i] * scale);
}

__global__ __launch_bounds__(256) void cvt_w3_tiled(
    const float* __restrict__ Wa, const float* __restrict__ Wb,
    const float* __restrict__ Wc, __hip_bfloat16* __restrict__ Wt,
    float scale_a)
{
    __shared__ float t[32][33];
    const int n0 = blockIdx.x * 32;
    const int k0 = blockIdx.y * 32;
    const float* W = (n0 < 256) ? Wa : (n0 < 512 ? Wb : Wc);
    const float sc = (n0 < 256) ? scale_a : 1.0f;
    const int ncol = n0 & 255;
    const int tx = threadIdx.x & 31;
    const int ty = threadIdx.x >> 5;
    #pragma unroll
    for (int i = 0; i < 32; i += 8)
        t[ty + i][tx] = W[(size_t)(k0 + ty + i) * 256 + ncol + tx];
    __syncthreads();
    #pragma unroll
    for (int i = 0; i < 32; i += 8)
        Wt[(size_t)(n0 + ty + i) * 256 + k0 + tx] = __float2bfloat16(t[tx][ty + i] * sc);
}

// biases + key_start prefix sums (batch offsets)
__global__ __launch_bounds__(768) void make_bqkv(
    const float* __restrict__ bq, const float* __restrict__ bk,
    const float* __restrict__ bv, const int* __restrict__ kbc, int nb,
    float* __restrict__ o, int* __restrict__ ks, float qs)
{
    int i = threadIdx.x;
    if (i < 256)      o[i] = bq[i] * qs;
    else if (i < 512) o[i] = bk[i - 256];
    else              o[i] = bv[i - 512];
    if (i < nb) {
        int acc = 0;
        for (int j = 0; j < i; ++j) acc += kbc[j];
        ks[i] = acc;
    }
}

// ---------------------------------------------------------------------------
// Gathered local attention: ONE WAVE per query, fully coalesced row gathers.
// (unchanged from round 9 — 210->169 us win)
// ---------------------------------------------------------------------------
__global__ __launch_bounds__(256) void attn_wave(
    const float* __restrict__ qf,
    const __hip_bfloat16* __restrict__ kvb,
    const int* __restrict__ index_pair,
    const int* __restrict__ ipb,
    const int* __restrict__ key_start,
    __hip_bfloat16* __restrict__ out)
{
    const int w    = threadIdx.x >> 6;
    const int lane = threadIdx.x & 63;
    const int bid  = blockIdx.x;
    const int n  = (bid & 7) * 2048 + (bid >> 3) * 4 + w;
    const int c  = lane & 31;      // dim chunk: dims [c*8, c*8+8)
    const int pp = lane >> 5;      // row parity

    int raw = index_pair[(size_t)n * LNEIGH + c];
    int ks  = key_start[ipb[n]];
    int gi0 = (raw >= 0) ? raw + ks : -1;

    const float* qp = qf + (size_t)n * 256 + c * 8;
    float4 q0 = *(const float4*)(qp);
    float4 q1 = *(const float4*)(qp + 4);

    int gi[16];
    #pragma unroll
    for (int i = 0; i < 16; ++i) gi[i] = __shfl(gi0, 2 * i + pp);

    bf16x8 kr[16];
    #pragma unroll
    for (int i = 0; i < 16; ++i) {
        int g = gi[i] < 0 ? 0 : gi[i];
        kr[i] = *(const bf16x8*)(kvb + (size_t)g * 512 + c * 8);
    }

    float s[16];
    #pragma unroll
    for (int i = 0; i < 16; ++i) {
        float t = q0.x * b2f(kr[i][0]) + q0.y * b2f(kr[i][1])
                + q0.z * b2f(kr[i][2]) + q0.w * b2f(kr[i][3])
                + q1.x * b2f(kr[i][4]) + q1.y * b2f(kr[i][5])
                + q1.z * b2f(kr[i][6]) + q1.w * b2f(kr[i][7]);
        t += __shfl_xor(t, 1);
        t += __shfl_xor(t, 2);
        s[i] = (gi[i] < 0) ? -1e9f : t;
    }

    bf16x8 vr[16];
    #pragma unroll
    for (int i = 0; i < 16; ++i) {
        int g = gi[i] < 0 ? 0 : gi[i];
        vr[i] = *(const bf16x8*)(kvb + (size_t)g * 512 + 256 + c * 8);
    }

    float m = s[0];
    #pragma unroll
    for (int i = 1; i < 16; ++i) m = fmaxf(m, s[i]);
    m = fmaxf(m, __shfl_xor(m, 32));
    float tot = 0.0f;
    #pragma unroll
    for (int i = 0; i < 16; ++i) { s[i] = __expf(s[i] - m); tot += s[i]; }
    tot += __shfl_xor(tot, 32);
    const float inv = 1.0f / tot;

    float a[8] = {};
    #pragma unroll
    for (int i = 0; i < 16; ++i) {
        float wt = s[i] * inv;
        #pragma unroll
        for (int j = 0; j < 8; ++j) a[j] += wt * b2f(vr[i][j]);
    }
    #pragma unroll
    for (int j = 0; j < 8; ++j) a[j] += __shfl_xor(a[j], 32);

    if (pp == 0) {
        bf16x8 ov;
        #pragma unroll
        for (int j = 0; j < 8; ++j)
            ov[j] = __builtin_bit_cast(short, __float2bfloat16(a[j]));
        *(bf16x8*)((short*)out + (size_t)n * 256 + c * 8) = ov;
    }
}

// ---------------------------------------------------------------------------
extern "C" void kernel_launch(void* const* d_in, const int* in_sizes, int n_in,
                              void* d_out, int out_size, void* d_ws, size_t ws_size,
                              hipStream_t stream)
{
    const float* src = (const float*)d_in[0];
    const int*   index_pair = (const int*)d_in[1];
    const int*   kbc = (const int*)d_in[3];
    const int*   ipb = (const int*)d_in[4];
    const float* Wq = (const float*)d_in[5];
    const float* bq = (const float*)d_in[6];
    const float* Wk = (const float*)d_in[7];
    const float* bk = (const float*)d_in[8];
    const float* Wv = (const float*)d_in[9];
    const float* bv = (const float*)d_in[10];
    const float* Wo = (const float*)d_in[11];
    const float* bo = (const float*)d_in[12];
    const float* W1 = (const float*)d_in[13];
    const float* b1 = (const float*)d_in[14];
    const float* W2 = (const float*)d_in[15];
    const float* b2 = (const float*)d_in[16];
    const float* g1 = (const float*)d_in[17];
    const float* be1 = (const float*)d_in[18];
    const float* g2 = (const float*)d_in[19];
    const float* be2 = (const float*)d_in[20];
    float* out = (float*)d_out;
    const int nb = in_sizes[3];   // number of batches

    char* ws = (char*)d_ws;
    // Attention-phase buffers die before FFN1; hc (64 MB at offset 0) aliases.
    const size_t O_SRCBF = 0;                        //  8.39 MB bf16 src
    const size_t O_QF    = 8388608;                  // 16.78 MB f32 q
    const size_t O_KVB   = 25165824;                 // 16.78 MB bf16 k|v
    const size_t O_ATTN  = 41943040;                 //  8.39 MB bf16 attn out
    const size_t O_HC    = 0;                        // 64 MB alias (FFN hidden)
    const size_t O_XBF   = 67108864;                 //  8.39 MB bf16 x (LN1 out)
    const size_t O_WQKV  = 75497472;
    const size_t O_WO    = O_WQKV + 768 * 256 * 2;
    const size_t O_W1    = O_WO + 256 * 256 * 2;
    const size_t O_W2    = O_W1 + (size_t)DFF * 256 * 2;
    const size_t O_BQKV  = O_W2 + (size_t)DFF * 256 * 2;
    const size_t O_KS    = O_BQKV + 768 * 4;

    __hip_bfloat16* src_bf  = (__hip_bfloat16*)(ws + O_SRCBF);
    float*          qf      = (float*)(ws + O_QF);
    __hip_bfloat16* kvb     = (__hip_bfloat16*)(ws + O_KVB);
    __hip_bfloat16* attn_bf = (__hip_bfloat16*)(ws + O_ATTN);
    __hip_bfloat16* hc      = (__hip_bfloat16*)(ws + O_HC);
    __hip_bfloat16* x_bf    = (__hip_bfloat16*)(ws + O_XBF);
    __hip_bfloat16* WqkvT   = (__hip_bfloat16*)(ws + O_WQKV);
    __hip_bfloat16* WoT     = (__hip_bfloat16*)(ws + O_WO);
    __hip_bfloat16* W1T     = (__hip_bfloat16*)(ws + O_W1);
    __hip_bfloat16* W2T     = (__hip_bfloat16*)(ws + O_W2);
    float*          bqkv    = (float*)(ws + O_BQKV);
    int*            ksbuf   = (int*)(ws + O_KS);

    const dim3 blk(256);
    const float qscale = 0.17677669529663687f;

    // allow the BM=32 BK=64 LN-GEMM its 72 KB of dynamic LDS
    hipFuncSetAttribute(reinterpret_cast<const void*>(gemm_bk64_ln32),
                        hipFuncAttributeMaxDynamicSharedMemorySize, SMEM_LN32);

    // --- conversions ---
    cvt_f2b<<<N_TOK * D_MODEL / 4 / 256, blk, 0, stream>>>(src, src_bf, N_TOK * D_MODEL);
    cvt_w3_tiled<<<dim3(24, 8), blk, 0, stream>>>(Wq, Wk, Wv, WqkvT, qscale);
    cvt_wt_tiled<<<dim3(8, 8),  blk, 0, stream>>>(Wo, WoT, 256, 256, 256, 1.0f);
    cvt_wt_tiled<<<dim3(64, 8), blk, 0, stream>>>(W1, W1T, 256, DFF, 256, 1.0f);
    cvt_wt_tiled<<<dim3(8, 64), blk, 0, stream>>>(W2, W2T, DFF, 256, DFF, 1.0f);
    make_bqkv<<<1, 768, 0, stream>>>(bq, bk, bv, kbc, nb, bqkv, ksbuf, qscale);

    // --- fused QKV projection: q -> f32 qf, k|v -> bf16 kvb ---
    gemm_qkv<<<dim3(6, 128), blk, 0, stream>>>(src_bf, WqkvT, bqkv, qf, kvb);

    // --- gathered attention (wave per query, coalesced row gathers) ---
    attn_wave<<<dim3(N_TOK / 4), blk, 0, stream>>>(qf, kvb, index_pair, ipb, ksbuf, attn_bf);

    // --- Wo + residual(src) + LN1 fused -> x_bf ---
    gemm_bk64_ln32<<<dim3(N_TOK / 32), dim3(512), SMEM_LN32, stream>>>(
        attn_bf, 256, WoT, 256, bo, src, nullptr, g1, be1,
        nullptr, x_bf, 256);

    // --- FFN1 (N=2048, relu) -> hc ---
    gemm_bt<<<dim3(16, 128), blk, 0, stream>>>(
        x_bf, 256, W1T, 256, b1, hc, DFF, N_TOK, DFF, 256, 1);

    // --- FFN2 + residual(x_bf) + LN2 fused -> out ---
    gemm_bk64_ln32<<<dim3(N_TOK / 32), dim3(512), SMEM_LN32, stream>>>(
        hc, DFF, W2T, DFF, b2, nullptr, x_bf, g2, be2,
        out, nullptr, DFF);
}

// Round 17
// 144.595 us; speedup vs baseline: 1.4760x; 1.0555x over previous
//
#include <hip/hip_runtime.h>
#include <hip/hip_bf16.h>
#include <cstddef>
#include <cstdint>

#define D_MODEL 256
#define N_TOK   16384
#define NHEAD   8
#define HDIM    32
#define LNEIGH  32
#define DFF     2048

// dynamic LDS for gemm_bk64_ln32: A dbuf 8K + B dbuf 64K (LN scratch aliases A)
#define SMEM_LN32 (8192 + 65536)   // 73728 B -> 2 blocks/CU

typedef short bf16x8 __attribute__((ext_vector_type(8)));
typedef float f32x4  __attribute__((ext_vector_type(4)));

__device__ __forceinline__ float b2f(short s) {
    unsigned u = ((unsigned)(unsigned short)s) << 16;
    return __builtin_bit_cast(float, u);
}

// global -> LDS async copy, 16B per lane; LDS fills base + lane*16.
__device__ __forceinline__ void gload_lds16(const void* g, void* l) {
    auto* gp = reinterpret_cast<const __attribute__((address_space(1))) uint32_t*>(
        reinterpret_cast<uintptr_t>(g));
    auto* lp = reinterpret_cast<__attribute__((address_space(3))) uint32_t*>(
        reinterpret_cast<uintptr_t>(l));
    __builtin_amdgcn_global_load_lds(gp, lp, 16, 0, 0);
}

// ---------------------------------------------------------------------------
// bf16 MFMA GEMM, 128x128 tile, 4 waves, double-buffered K-loop.
// C = A[M,K] @ Bt[N,K]^T. Epilogue: +bias, relu, bf16 out (pitch ldc).
// XOR chunk-swizzle both sides (src chunk ^= row&3; read chunk = hi^(lane&3))
// cuts the 8-way ds_read_b128 conflict to 4-way (m98: 1.7e7 conflicts here).
// ---------------------------------------------------------------------------
__global__ __launch_bounds__(256) void gemm_bt(
    const __hip_bfloat16* __restrict__ A, int lda,
    const __hip_bfloat16* __restrict__ Bt, int ldb,
    const float* __restrict__ bias,
    __hip_bfloat16* __restrict__ outb, int ldc,
    int M, int N, int K, int relu)
{
    __shared__ short Asm[2][128 * 32];
    __shared__ short Bsm[2][128 * 32];

    const int tid  = threadIdx.x;
    const int lane = tid & 63;
    const int wid  = tid >> 6;
    const int wr   = wid >> 1;
    const int wc   = wid & 1;
    const int bm   = blockIdx.y * 128;
    const int bn   = blockIdx.x * 128;

    f32x4 acc[4][4] = {};
    const int srow = lane >> 2;                          // 0..15 row in stripe
    const int seg  = (((lane & 3) ^ (srow & 3)) << 3);   // swizzled source chunk

    auto stage = [&](int buf, int k0) {
        #pragma unroll
        for (int t = 0; t < 2; ++t) {
            int rbase = wid * 32 + t * 16;
            gload_lds16(A  + (size_t)(bm + rbase + srow) * lda + k0 + seg, &Asm[buf][rbase * 32]);
            gload_lds16(Bt + (size_t)(bn + rbase + srow) * ldb + k0 + seg, &Bsm[buf][rbase * 32]);
        }
    };

    const int nk = K >> 5;
    stage(0, 0);
    __syncthreads();

    // read: row = <mult of 16> + (lane&15), global chunk hi=lane>>4;
    // LDS[row][c] holds global chunk c^(row&3), row&3 == lane&3
    const int csw = (((lane >> 4) ^ (lane & 3)) << 3);

    for (int kk = 0; kk < nk; ++kk) {
        const int cur = kk & 1;
        if (kk + 1 < nk) stage(cur ^ 1, (kk + 1) << 5);

        bf16x8 a[4], b[4];
        #pragma unroll
        for (int i = 0; i < 4; ++i)
            a[i] = *(const bf16x8*)&Asm[cur][(wr * 64 + i * 16 + (lane & 15)) * 32 + csw];
        #pragma unroll
        for (int j = 0; j < 4; ++j)
            b[j] = *(const bf16x8*)&Bsm[cur][(wc * 64 + j * 16 + (lane & 15)) * 32 + csw];
        #pragma unroll
        for (int i = 0; i < 4; ++i)
            #pragma unroll
            for (int j = 0; j < 4; ++j)
                acc[i][j] = __builtin_amdgcn_mfma_f32_16x16x32_bf16(a[i], b[j], acc[i][j], 0, 0, 0);
        __syncthreads();
    }

    #pragma unroll
    for (int i = 0; i < 4; ++i) {
        int rbase = bm + wr * 64 + i * 16 + ((lane >> 4) << 2);
        #pragma unroll
        for (int j = 0; j < 4; ++j) {
            int col = bn + wc * 64 + j * 16 + (lane & 15);
            float bval = bias ? bias[col] : 0.0f;
            #pragma unroll
            for (int r = 0; r < 4; ++r) {
                int row = rbase + r;
                float v = acc[i][j][r] + bval;
                if (relu) v = fmaxf(v, 0.0f);
                outb[(size_t)row * ldc + col] = __float2bfloat16(v);
            }
        }
    }
}

// ---------------------------------------------------------------------------
// BK=64 LN-GEMM, BM=32: N=256, 8 waves (2x4), wave = 16x64.
// Grid = M/32 = 512 blocks; dynamic LDS 72 KB -> 2 blocks/CU (verified round 16:
// 160->152.6 us). XOR swizzle both sides -> 0 conflicts (round-14 verified).
// LN scratch aliases the dead A buffer. Fused bias+residual+LayerNorm.
// ---------------------------------------------------------------------------
__global__ __launch_bounds__(512) void gemm_bk64_ln32(
    const __hip_bfloat16* __restrict__ A, int lda,
    const __hip_bfloat16* __restrict__ Bt, int ldb,
    const float* __restrict__ bias,
    const float* __restrict__ residf,
    const __hip_bfloat16* __restrict__ residb,
    const float* __restrict__ g,
    const float* __restrict__ be,
    float* __restrict__ outf,
    __hip_bfloat16* __restrict__ outb,
    int K)
{
    extern __shared__ char smem[];
    short* AsmB = (short*)smem;                      // [2][32*64]   8 KB
    short* BsmB = (short*)(smem + 8192);             // [2][256*64]  64 KB
    float* lnS  = (float*)smem;                      // aliases A (dead post-loop)
    float* lnS2 = (float*)(smem + 1024);
    float* rmu  = (float*)(smem + 2048);
    float* rrs  = (float*)(smem + 2176);

    const int tid  = threadIdx.x;
    const int lane = tid & 63;
    const int wid  = tid >> 6;           // 0..7
    const int wr   = wid >> 2;           // 0..1 (16-row half)
    const int wc   = wid & 3;            // 0..3 (64-col quarter)
    const int bm   = blockIdx.x * 32;
    const int lo   = lane & 15;
    const int hi   = lane >> 4;

    f32x4 acc[4] = {};

    const int srow8 = lane >> 3;         // row within stripe
    const int sc    = lane & 7;          // chunk slot
    const int ssw   = ((sc ^ srow8) << 3);

    auto stage = [&](int buf, int k0) {
        if (wid < 4)
            gload_lds16(A + (size_t)(bm + wid * 8 + srow8) * lda + k0 + ssw,
                        AsmB + buf * 2048 + (wid * 8) * 64);
        #pragma unroll
        for (int t = 0; t < 4; ++t) {
            int rb = wid * 32 + t * 8;
            gload_lds16(Bt + (size_t)(rb + srow8) * ldb + k0 + ssw,
                        BsmB + buf * 16384 + rb * 64);
        }
    };

    const int nk = K >> 6;
    stage(0, 0);
    __syncthreads();

    for (int kk = 0; kk < nk; ++kk) {
        const int cur = kk & 1;
        if (kk + 1 < nk) stage(cur ^ 1, (kk + 1) << 6);

        const short* Ab = AsmB + cur * 2048;
        const short* Bb = BsmB + cur * 16384;
        #pragma unroll
        for (int ks = 0; ks < 2; ++ks) {
            const int csw = ((ks * 4 + hi) ^ (lo & 7)) << 3;
            bf16x8 a = *(const bf16x8*)&Ab[(wr * 16 + lo) * 64 + csw];
            bf16x8 b[4];
            #pragma unroll
            for (int j = 0; j < 4; ++j)
                b[j] = *(const bf16x8*)&Bb[(wc * 64 + j * 16 + lo) * 64 + csw];
            #pragma unroll
            for (int j = 0; j < 4; ++j)
                acc[j] = __builtin_amdgcn_mfma_f32_16x16x32_bf16(a, b[j], acc[j], 0, 0, 0);
        }
        __syncthreads();
    }

    float ps[4] = {}, ps2[4] = {};
    #pragma unroll
    for (int j = 0; j < 4; ++j) {
        int col = wc * 64 + j * 16 + lo;
        float bval = bias ? bias[col] : 0.0f;
        #pragma unroll
        for (int r = 0; r < 4; ++r) {
            int row = bm + wr * 16 + hi * 4 + r;
            float v = acc[j][r] + bval;
            size_t o = (size_t)row * 256 + col;
            if (residf) v += residf[o];
            if (residb) v += __bfloat162float(residb[o]);
            acc[j][r] = v;
            ps[r]  += v;
            ps2[r] += v * v;
        }
    }
    #pragma unroll
    for (int r = 0; r < 4; ++r) {
        #pragma unroll
        for (int m = 1; m < 16; m <<= 1) {
            ps[r]  += __shfl_xor(ps[r],  m);
            ps2[r] += __shfl_xor(ps2[r], m);
        }
    }
    if (lo == 0) {
        #pragma unroll
        for (int r = 0; r < 4; ++r) {
            int rl = wr * 16 + hi * 4 + r;
            lnS[wid * 32 + rl]  = ps[r];
            lnS2[wid * 32 + rl] = ps2[r];
        }
    }
    __syncthreads();
    if (tid < 32) {
        int base = (tid >> 4) * 4;
        float s  = lnS[base * 32 + tid] + lnS[(base + 1) * 32 + tid]
                 + lnS[(base + 2) * 32 + tid] + lnS[(base + 3) * 32 + tid];
        float s2 = lnS2[base * 32 + tid] + lnS2[(base + 1) * 32 + tid]
                 + lnS2[(base + 2) * 32 + tid] + lnS2[(base + 3) * 32 + tid];
        float mu  = s * (1.0f / 256.0f);
        float var = s2 * (1.0f / 256.0f) - mu * mu;
        rmu[tid] = mu;
        rrs[tid] = rsqrtf(var + 1e-5f);
    }
    __syncthreads();

    #pragma unroll
    for (int j = 0; j < 4; ++j) {
        int col = wc * 64 + j * 16 + lo;
        float gg = g[col], bb = be[col];
        #pragma unroll
        for (int r = 0; r < 4; ++r) {
            int rl = wr * 16 + hi * 4 + r;
            float v = (acc[j][r] - rmu[rl]) * rrs[rl] * gg + bb;
            size_t o = (size_t)(bm + rl) * 256 + col;
            if (outf) outf[o] = v;
            if (outb) outb[o] = __float2bfloat16(v);
        }
    }
}

// ---------------------------------------------------------------------------
// QKV GEMM: C = src_bf @ WqkvT^T (N=768, K=256), split epilogue; swizzled LDS.
// ---------------------------------------------------------------------------
__global__ __launch_bounds__(256) void gemm_qkv(
    const __hip_bfloat16* __restrict__ A,
    const __hip_bfloat16* __restrict__ Bt,
    const float* __restrict__ bias,
    float* __restrict__ qf,
    __hip_bfloat16* __restrict__ kvb)
{
    __shared__ short Asm[2][128 * 32];
    __shared__ short Bsm[2][128 * 32];

    const int tid  = threadIdx.x;
    const int lane = tid & 63;
    const int wid  = tid >> 6;
    const int wr   = wid >> 1;
    const int wc   = wid & 1;
    const int bm   = blockIdx.y * 128;
    const int bn   = blockIdx.x * 128;

    f32x4 acc[4][4] = {};
    const int srow = lane >> 2;
    const int seg  = (((lane & 3) ^ (srow & 3)) << 3);

    auto stage = [&](int buf, int k0) {
        #pragma unroll
        for (int t = 0; t < 2; ++t) {
            int rbase = wid * 32 + t * 16;
            gload_lds16(A  + (size_t)(bm + rbase + srow) * 256 + k0 + seg, &Asm[buf][rbase * 32]);
            gload_lds16(Bt + (size_t)(bn + rbase + srow) * 256 + k0 + seg, &Bsm[buf][rbase * 32]);
        }
    };

    stage(0, 0);
    __syncthreads();
    const int csw = (((lane >> 4) ^ (lane & 3)) << 3);
    for (int kk = 0; kk < 8; ++kk) {
        const int cur = kk & 1;
        if (kk + 1 < 8) stage(cur ^ 1, (kk + 1) << 5);
        bf16x8 a[4], b[4];
        #pragma unroll
        for (int i = 0; i < 4; ++i)
            a[i] = *(const bf16x8*)&Asm[cur][(wr * 64 + i * 16 + (lane & 15)) * 32 + csw];
        #pragma unroll
        for (int j = 0; j < 4; ++j)
            b[j] = *(const bf16x8*)&Bsm[cur][(wc * 64 + j * 16 + (lane & 15)) * 32 + csw];
        #pragma unroll
        for (int i = 0; i < 4; ++i)
            #pragma unroll
            for (int j = 0; j < 4; ++j)
                acc[i][j] = __builtin_amdgcn_mfma_f32_16x16x32_bf16(a[i], b[j], acc[i][j], 0, 0, 0);
        __syncthreads();
    }

    const bool isq = (bn < 256);
    #pragma unroll
    for (int i = 0; i < 4; ++i) {
        int rbase = bm + wr * 64 + i * 16 + ((lane >> 4) << 2);
        #pragma unroll
        for (int j = 0; j < 4; ++j) {
            int col = bn + wc * 64 + j * 16 + (lane & 15);
            float bval = bias[col];
            #pragma unroll
            for (int r = 0; r < 4; ++r) {
                int row = rbase + r;
                float v = acc[i][j][r] + bval;
                if (isq) qf[(size_t)row * 256 + col] = v;
                else     kvb[(size_t)row * 512 + (col - 256)] = __float2bfloat16(v);
            }
        }
    }
}

// ---------------------------------------------------------------------------
__global__ __launch_bounds__(256) void cvt_f2b(
    const float* __restrict__ x, __hip_bfloat16* __restrict__ y, int n)
{
    int i = (blockIdx.x * 256 + threadIdx.x) * 4;
    if (i >= n) return;
    float4 v = *(const float4*)(x + i);
    y[i + 0] = __float2bfloat16(v.x);
    y[i + 1] = __float2bfloat16(v.y);
    y[i + 2] = __float2bfloat16(v.z);
    y[i + 3] = __float2bfloat16(v.w);
}

// ---------------------------------------------------------------------------
// ALL weight conversions + biases + key_start in ONE dispatch (1281 blocks):
//   [0,192)      Wq|Wk|Wv -> WqkvT[768][256] (q scaled)
//   [192,256)    Wo -> WoT[256][256]
//   [256,768)    W1 -> W1T[2048][256]
//   [768,1280)   W2 -> W2T[256][2048]
//   1280         bqkv (768) + key_start prefix sums
// ---------------------------------------------------------------------------
__global__ __launch_bounds__(256) void cvt_all(
    const float* __restrict__ Wq, const float* __restrict__ Wk,
    const float* __restrict__ Wv, const float* __restrict__ Wo,
    const float* __restrict__ W1, const float* __restrict__ W2,
    const float* __restrict__ bq, const float* __restrict__ bk,
    const float* __restrict__ bv, const int* __restrict__ kbc, int nb,
    __hip_bfloat16* __restrict__ WqkvT, __hip_bfloat16* __restrict__ WoT,
    __hip_bfloat16* __restrict__ W1T,   __hip_bfloat16* __restrict__ W2T,
    float* __restrict__ bqkv, int* __restrict__ ks, float qs)
{
    const int b = blockIdx.x;
    if (b == 1280) {
        int i = threadIdx.x;
        #pragma unroll
        for (int t = 0; t < 3; ++t, i += 256) {
            if (i < 256)      bqkv[i] = bq[i] * qs;
            else if (i < 512) bqkv[i] = bk[i - 256];
            else              bqkv[i] = bv[i - 512];
        }
        i = threadIdx.x;
        if (i < nb) {
            int acc = 0;
            for (int j = 0; j < i; ++j) acc += kbc[j];
            ks[i] = acc;
        }
        return;
    }

    const float* W; __hip_bfloat16* Wt; int K, N, ldo, n0, k0; float sc = 1.0f;
    if (b < 192) {            // Wqkv: grid (24 x 8)
        int i = b; n0 = (i % 24) * 32; k0 = (i / 24) * 32;
        K = 256; N = 256; ldo = 256;
        W = (n0 < 256) ? Wq : (n0 < 512 ? Wk : Wv);
        sc = (n0 < 256) ? qs : 1.0f;
        Wt = WqkvT; // note: n0 indexes the 768-row output; source col = n0 & 255
    } else if (b < 256) {     // Wo: grid (8 x 8)
        int i = b - 192; n0 = (i % 8) * 32; k0 = (i / 8) * 32;
        K = 256; N = 256; ldo = 256; W = Wo; Wt = WoT;
    } else if (b < 768) {     // W1: grid (64 x 8)
        int i = b - 256; n0 = (i % 64) * 32; k0 = (i / 64) * 32;
        K = 256; N = DFF; ldo = 256; W = W1; Wt = W1T;
    } else {                  // W2: grid (8 x 64)
        int i = b - 768; n0 = (i % 8) * 32; k0 = (i / 8) * 32;
        K = DFF; N = 256; ldo = DFF; W = W2; Wt = W2T;
    }
    const int ncol = (b < 192) ? (n0 & 255) : n0;

    __shared__ float t[32][33];
    const int tx = threadIdx.x & 31;
    const int ty = threadIdx.x >> 5;
    #pragma unroll
    for (int i = 0; i < 32; i += 8)
        t[ty + i][tx] = W[(size_t)(k0 + ty + i) * N + ncol + tx];
    __syncthreads();
    #pragma unroll
    for (int i = 0; i < 32; i += 8)
        Wt[(size_t)(n0 + ty + i) * ldo + k0 + tx] = __float2bfloat16(t[tx][ty + i] * sc);
}

// ---------------------------------------------------------------------------
// Gathered local attention: ONE WAVE per query, fully coalesced row gathers.
// (unchanged from round 9)
// ---------------------------------------------------------------------------
__global__ __launch_bounds__(256) void attn_wave(
    const float* __restrict__ qf,
    const __hip_bfloat16* __restrict__ kvb,
    const int* __restrict__ index_pair,
    const int* __restrict__ ipb,
    const int* __restrict__ key_start,
    __hip_bfloat16* __restrict__ out)
{
    const int w    = threadIdx.x >> 6;
    const int lane = threadIdx.x & 63;
    const int bid  = blockIdx.x;
    const int n  = (bid & 7) * 2048 + (bid >> 3) * 4 + w;
    const int c  = lane & 31;
    const int pp = lane >> 5;

    int raw = index_pair[(size_t)n * LNEIGH + c];
    int ks  = key_start[ipb[n]];
    int gi0 = (raw >= 0) ? raw + ks : -1;

    const float* qp = qf + (size_t)n * 256 + c * 8;
    float4 q0 = *(const float4*)(qp);
    float4 q1 = *(const float4*)(qp + 4);

    int gi[16];
    #pragma unroll
    for (int i = 0; i < 16; ++i) gi[i] = __shfl(gi0, 2 * i + pp);

    bf16x8 kr[16];
    #pragma unroll
    for (int i = 0; i < 16; ++i) {
        int g = gi[i] < 0 ? 0 : gi[i];
        kr[i] = *(const bf16x8*)(kvb + (size_t)g * 512 + c * 8);
    }

    float s[16];
    #pragma unroll
    for (int i = 0; i < 16; ++i) {
        float t = q0.x * b2f(kr[i][0]) + q0.y * b2f(kr[i][1])
                + q0.z * b2f(kr[i][2]) + q0.w * b2f(kr[i][3])
                + q1.x * b2f(kr[i][4]) + q1.y * b2f(kr[i][5])
                + q1.z * b2f(kr[i][6]) + q1.w * b2f(kr[i][7]);
        t += __shfl_xor(t, 1);
        t += __shfl_xor(t, 2);
        s[i] = (gi[i] < 0) ? -1e9f : t;
    }

    bf16x8 vr[16];
    #pragma unroll
    for (int i = 0; i < 16; ++i) {
        int g = gi[i] < 0 ? 0 : gi[i];
        vr[i] = *(const bf16x8*)(kvb + (size_t)g * 512 + 256 + c * 8);
    }

    float m = s[0];
    #pragma unroll
    for (int i = 1; i < 16; ++i) m = fmaxf(m, s[i]);
    m = fmaxf(m, __shfl_xor(m, 32));
    float tot = 0.0f;
    #pragma unroll
    for (int i = 0; i < 16; ++i) { s[i] = __expf(s[i] - m); tot += s[i]; }
    tot += __shfl_xor(tot, 32);
    const float inv = 1.0f / tot;

    float a[8] = {};
    #pragma unroll
    for (int i = 0; i < 16; ++i) {
        float wt = s[i] * inv;
        #pragma unroll
        for (int j = 0; j < 8; ++j) a[j] += wt * b2f(vr[i][j]);
    }
    #pragma unroll
    for (int j = 0; j < 8; ++j) a[j] += __shfl_xor(a[j], 32);

    if (pp == 0) {
        bf16x8 ov;
        #pragma unroll
        for (int j = 0; j < 8; ++j)
            ov[j] = __builtin_bit_cast(short, __float2bfloat16(a[j]));
        *(bf16x8*)((short*)out + (size_t)n * 256 + c * 8) = ov;
    }
}

// ---------------------------------------------------------------------------
extern "C" void kernel_launch(void* const* d_in, const int* in_sizes, int n_in,
                              void* d_out, int out_size, void* d_ws, size_t ws_size,
                              hipStream_t stream)
{
    const float* src = (const float*)d_in[0];
    const int*   index_pair = (const int*)d_in[1];
    const int*   kbc = (const int*)d_in[3];
    const int*   ipb = (const int*)d_in[4];
    const float* Wq = (const float*)d_in[5];
    const float* bq = (const float*)d_in[6];
    const float* Wk = (const float*)d_in[7];
    const float* bk = (const float*)d_in[8];
    const float* Wv = (const float*)d_in[9];
    const float* bv = (const float*)d_in[10];
    const float* Wo = (const float*)d_in[11];
    const float* bo = (const float*)d_in[12];
    const float* W1 = (const float*)d_in[13];
    const float* b1 = (const float*)d_in[14];
    const float* W2 = (const float*)d_in[15];
    const float* b2 = (const float*)d_in[16];
    const float* g1 = (const float*)d_in[17];
    const float* be1 = (const float*)d_in[18];
    const float* g2 = (const float*)d_in[19];
    const float* be2 = (const float*)d_in[20];
    float* out = (float*)d_out;
    const int nb = in_sizes[3];

    char* ws = (char*)d_ws;
    const size_t O_SRCBF = 0;                        //  8.39 MB bf16 src
    const size_t O_QF    = 8388608;                  // 16.78 MB f32 q
    const size_t O_KVB   = 25165824;                 // 16.78 MB bf16 k|v
    const size_t O_ATTN  = 41943040;                 //  8.39 MB bf16 attn out
    const size_t O_HC    = 0;                        // 64 MB alias (FFN hidden)
    const size_t O_XBF   = 67108864;                 //  8.39 MB bf16 x (LN1 out)
    const size_t O_WQKV  = 75497472;
    const size_t O_WO    = O_WQKV + 768 * 256 * 2;
    const size_t O_W1    = O_WO + 256 * 256 * 2;
    const size_t O_W2    = O_W1 + (size_t)DFF * 256 * 2;
    const size_t O_BQKV  = O_W2 + (size_t)DFF * 256 * 2;
    const size_t O_KS    = O_BQKV + 768 * 4;

    __hip_bfloat16* src_bf  = (__hip_bfloat16*)(ws + O_SRCBF);
    float*          qf      = (float*)(ws + O_QF);
    __hip_bfloat16* kvb     = (__hip_bfloat16*)(ws + O_KVB);
    __hip_bfloat16* attn_bf = (__hip_bfloat16*)(ws + O_ATTN);
    __hip_bfloat16* hc      = (__hip_bfloat16*)(ws + O_HC);
    __hip_bfloat16* x_bf    = (__hip_bfloat16*)(ws + O_XBF);
    __hip_bfloat16* WqkvT   = (__hip_bfloat16*)(ws + O_WQKV);
    __hip_bfloat16* WoT     = (__hip_bfloat16*)(ws + O_WO);
    __hip_bfloat16* W1T     = (__hip_bfloat16*)(ws + O_W1);
    __hip_bfloat16* W2T     = (__hip_bfloat16*)(ws + O_W2);
    float*          bqkv    = (float*)(ws + O_BQKV);
    int*            ksbuf   = (int*)(ws + O_KS);

    const dim3 blk(256);
    const float qscale = 0.17677669529663687f;

    hipFuncSetAttribute(reinterpret_cast<const void*>(gemm_bk64_ln32),
                        hipFuncAttributeMaxDynamicSharedMemorySize, SMEM_LN32);

    // --- conversions (2 dispatches) ---
    cvt_f2b<<<N_TOK * D_MODEL / 4 / 256, blk, 0, stream>>>(src, src_bf, N_TOK * D_MODEL);
    cvt_all<<<1281, blk, 0, stream>>>(Wq, Wk, Wv, Wo, W1, W2, bq, bk, bv, kbc, nb,
                                      WqkvT, WoT, W1T, W2T, bqkv, ksbuf, qscale);

    // --- fused QKV projection: q -> f32 qf, k|v -> bf16 kvb ---
    gemm_qkv<<<dim3(6, 128), blk, 0, stream>>>(src_bf, WqkvT, bqkv, qf, kvb);

    // --- gathered attention (wave per query, coalesced row gathers) ---
    attn_wave<<<dim3(N_TOK / 4), blk, 0, stream>>>(qf, kvb, index_pair, ipb, ksbuf, attn_bf);

    // --- Wo + residual(src) + LN1 fused -> x_bf ---
    gemm_bk64_ln32<<<dim3(N_TOK / 32), dim3(512), SMEM_LN32, stream>>>(
        attn_bf, 256, WoT, 256, bo, src, nullptr, g1, be1,
        nullptr, x_bf, 256);

    // --- FFN1 (N=2048, relu) -> hc ---
    gemm_bt<<<dim3(16, 128), blk, 0, stream>>>(
        x_bf, 256, W1T, 256, b1, hc, DFF, N_TOK, DFF, 256, 1);

    // --- FFN2 + residual(x_bf) + LN2 fused -> out ---
    gemm_bk64_ln32<<<dim3(N_TOK / 32), dim3(512), SMEM_LN32, stream>>>(
        hc, DFF, W2T, DFF, b2, nullptr, x_bf, g2, be2,
        out, nullptr, DFF);
}

// Round 18
// 142.101 us; speedup vs baseline: 1.5019x; 1.0176x over previous
//
#include <hip/hip_runtime.h>
#include <hip/hip_bf16.h>
#include <cstddef>
#include <cstdint>

#define D_MODEL 256
#define N_TOK   16384
#define NHEAD   8
#define HDIM    32
#define LNEIGH  32
#define DFF     2048

// dynamic LDS for gemm_bk64_ln32: A dbuf 8K + B dbuf 64K (LN scratch aliases A)
#define SMEM_LN32 (8192 + 65536)   // 73728 B -> 2 blocks/CU

typedef short bf16x8 __attribute__((ext_vector_type(8)));
typedef float f32x4  __attribute__((ext_vector_type(4)));

__device__ __forceinline__ float b2f(short s) {
    unsigned u = ((unsigned)(unsigned short)s) << 16;
    return __builtin_bit_cast(float, u);
}

// global -> LDS async copy, 16B per lane; LDS fills base + lane*16.
__device__ __forceinline__ void gload_lds16(const void* g, void* l) {
    auto* gp = reinterpret_cast<const __attribute__((address_space(1))) uint32_t*>(
        reinterpret_cast<uintptr_t>(g));
    auto* lp = reinterpret_cast<__attribute__((address_space(3))) uint32_t*>(
        reinterpret_cast<uintptr_t>(l));
    __builtin_amdgcn_global_load_lds(gp, lp, 16, 0, 0);
}

// ---------------------------------------------------------------------------
// bf16 MFMA GEMM, 128x128 tile, 4 waves, double-buffered K-loop, swizzled LDS.
// C = A[M,K] @ Bt[N,K]^T. Epilogue: +bias, relu, bf16 out (pitch ldc).
// ---------------------------------------------------------------------------
__global__ __launch_bounds__(256) void gemm_bt(
    const __hip_bfloat16* __restrict__ A, int lda,
    const __hip_bfloat16* __restrict__ Bt, int ldb,
    const float* __restrict__ bias,
    __hip_bfloat16* __restrict__ outb, int ldc,
    int M, int N, int K, int relu)
{
    __shared__ short Asm[2][128 * 32];
    __shared__ short Bsm[2][128 * 32];

    const int tid  = threadIdx.x;
    const int lane = tid & 63;
    const int wid  = tid >> 6;
    const int wr   = wid >> 1;
    const int wc   = wid & 1;
    const int bm   = blockIdx.y * 128;
    const int bn   = blockIdx.x * 128;

    f32x4 acc[4][4] = {};
    const int srow = lane >> 2;
    const int seg  = (((lane & 3) ^ (srow & 3)) << 3);   // swizzled source chunk

    auto stage = [&](int buf, int k0) {
        #pragma unroll
        for (int t = 0; t < 2; ++t) {
            int rbase = wid * 32 + t * 16;
            gload_lds16(A  + (size_t)(bm + rbase + srow) * lda + k0 + seg, &Asm[buf][rbase * 32]);
            gload_lds16(Bt + (size_t)(bn + rbase + srow) * ldb + k0 + seg, &Bsm[buf][rbase * 32]);
        }
    };

    const int nk = K >> 5;
    stage(0, 0);
    __syncthreads();

    const int csw = (((lane >> 4) ^ (lane & 3)) << 3);   // swizzled read chunk

    for (int kk = 0; kk < nk; ++kk) {
        const int cur = kk & 1;
        if (kk + 1 < nk) stage(cur ^ 1, (kk + 1) << 5);

        bf16x8 a[4], b[4];
        #pragma unroll
        for (int i = 0; i < 4; ++i)
            a[i] = *(const bf16x8*)&Asm[cur][(wr * 64 + i * 16 + (lane & 15)) * 32 + csw];
        #pragma unroll
        for (int j = 0; j < 4; ++j)
            b[j] = *(const bf16x8*)&Bsm[cur][(wc * 64 + j * 16 + (lane & 15)) * 32 + csw];
        #pragma unroll
        for (int i = 0; i < 4; ++i)
            #pragma unroll
            for (int j = 0; j < 4; ++j)
                acc[i][j] = __builtin_amdgcn_mfma_f32_16x16x32_bf16(a[i], b[j], acc[i][j], 0, 0, 0);
        __syncthreads();
    }

    #pragma unroll
    for (int i = 0; i < 4; ++i) {
        int rbase = bm + wr * 64 + i * 16 + ((lane >> 4) << 2);
        #pragma unroll
        for (int j = 0; j < 4; ++j) {
            int col = bn + wc * 64 + j * 16 + (lane & 15);
            float bval = bias ? bias[col] : 0.0f;
            #pragma unroll
            for (int r = 0; r < 4; ++r) {
                int row = rbase + r;
                float v = acc[i][j][r] + bval;
                if (relu) v = fmaxf(v, 0.0f);
                outb[(size_t)row * ldc + col] = __float2bfloat16(v);
            }
        }
    }
}

// ---------------------------------------------------------------------------
// BK=64 LN-GEMM, BM=32: N=256, 8 waves (2x4), wave = 16x64. 72 KB dynamic LDS
// -> 2 blocks/CU (round-16 verified). Swizzle both sides -> 0 conflicts.
// LN scratch aliases the dead A buffer. Fused bias+residual+LayerNorm.
// ---------------------------------------------------------------------------
__global__ __launch_bounds__(512) void gemm_bk64_ln32(
    const __hip_bfloat16* __restrict__ A, int lda,
    const __hip_bfloat16* __restrict__ Bt, int ldb,
    const float* __restrict__ bias,
    const float* __restrict__ residf,
    const __hip_bfloat16* __restrict__ residb,
    const float* __restrict__ g,
    const float* __restrict__ be,
    float* __restrict__ outf,
    __hip_bfloat16* __restrict__ outb,
    int K)
{
    extern __shared__ char smem[];
    short* AsmB = (short*)smem;                      // [2][32*64]   8 KB
    short* BsmB = (short*)(smem + 8192);             // [2][256*64]  64 KB
    float* lnS  = (float*)smem;                      // aliases A (dead post-loop)
    float* lnS2 = (float*)(smem + 1024);
    float* rmu  = (float*)(smem + 2048);
    float* rrs  = (float*)(smem + 2176);

    const int tid  = threadIdx.x;
    const int lane = tid & 63;
    const int wid  = tid >> 6;
    const int wr   = wid >> 2;
    const int wc   = wid & 3;
    const int bm   = blockIdx.x * 32;
    const int lo   = lane & 15;
    const int hi   = lane >> 4;

    f32x4 acc[4] = {};

    const int srow8 = lane >> 3;
    const int sc    = lane & 7;
    const int ssw   = ((sc ^ srow8) << 3);

    auto stage = [&](int buf, int k0) {
        if (wid < 4)
            gload_lds16(A + (size_t)(bm + wid * 8 + srow8) * lda + k0 + ssw,
                        AsmB + buf * 2048 + (wid * 8) * 64);
        #pragma unroll
        for (int t = 0; t < 4; ++t) {
            int rb = wid * 32 + t * 8;
            gload_lds16(Bt + (size_t)(rb + srow8) * ldb + k0 + ssw,
                        BsmB + buf * 16384 + rb * 64);
        }
    };

    const int nk = K >> 6;
    stage(0, 0);
    __syncthreads();

    for (int kk = 0; kk < nk; ++kk) {
        const int cur = kk & 1;
        if (kk + 1 < nk) stage(cur ^ 1, (kk + 1) << 6);

        const short* Ab = AsmB + cur * 2048;
        const short* Bb = BsmB + cur * 16384;
        #pragma unroll
        for (int ks = 0; ks < 2; ++ks) {
            const int csw = ((ks * 4 + hi) ^ (lo & 7)) << 3;
            bf16x8 a = *(const bf16x8*)&Ab[(wr * 16 + lo) * 64 + csw];
            bf16x8 b[4];
            #pragma unroll
            for (int j = 0; j < 4; ++j)
                b[j] = *(const bf16x8*)&Bb[(wc * 64 + j * 16 + lo) * 64 + csw];
            #pragma unroll
            for (int j = 0; j < 4; ++j)
                acc[j] = __builtin_amdgcn_mfma_f32_16x16x32_bf16(a, b[j], acc[j], 0, 0, 0);
        }
        __syncthreads();
    }

    float ps[4] = {}, ps2[4] = {};
    #pragma unroll
    for (int j = 0; j < 4; ++j) {
        int col = wc * 64 + j * 16 + lo;
        float bval = bias ? bias[col] : 0.0f;
        #pragma unroll
        for (int r = 0; r < 4; ++r) {
            int row = bm + wr * 16 + hi * 4 + r;
            float v = acc[j][r] + bval;
            size_t o = (size_t)row * 256 + col;
            if (residf) v += residf[o];
            if (residb) v += __bfloat162float(residb[o]);
            acc[j][r] = v;
            ps[r]  += v;
            ps2[r] += v * v;
        }
    }
    #pragma unroll
    for (int r = 0; r < 4; ++r) {
        #pragma unroll
        for (int m = 1; m < 16; m <<= 1) {
            ps[r]  += __shfl_xor(ps[r],  m);
            ps2[r] += __shfl_xor(ps2[r], m);
        }
    }
    if (lo == 0) {
        #pragma unroll
        for (int r = 0; r < 4; ++r) {
            int rl = wr * 16 + hi * 4 + r;
            lnS[wid * 32 + rl]  = ps[r];
            lnS2[wid * 32 + rl] = ps2[r];
        }
    }
    __syncthreads();
    if (tid < 32) {
        int base = (tid >> 4) * 4;
        float s  = lnS[base * 32 + tid] + lnS[(base + 1) * 32 + tid]
                 + lnS[(base + 2) * 32 + tid] + lnS[(base + 3) * 32 + tid];
        float s2 = lnS2[base * 32 + tid] + lnS2[(base + 1) * 32 + tid]
                 + lnS2[(base + 2) * 32 + tid] + lnS2[(base + 3) * 32 + tid];
        float mu  = s * (1.0f / 256.0f);
        float var = s2 * (1.0f / 256.0f) - mu * mu;
        rmu[tid] = mu;
        rrs[tid] = rsqrtf(var + 1e-5f);
    }
    __syncthreads();

    #pragma unroll
    for (int j = 0; j < 4; ++j) {
        int col = wc * 64 + j * 16 + lo;
        float gg = g[col], bb = be[col];
        #pragma unroll
        for (int r = 0; r < 4; ++r) {
            int rl = wr * 16 + hi * 4 + r;
            float v = (acc[j][r] - rmu[rl]) * rrs[rl] * gg + bb;
            size_t o = (size_t)(bm + rl) * 256 + col;
            if (outf) outf[o] = v;
            if (outb) outb[o] = __float2bfloat16(v);
        }
    }
}

// ---------------------------------------------------------------------------
// QKV GEMM: C = src_bf @ WqkvT^T (N=768, K=256), split epilogue; swizzled LDS.
// cols [0,256)  -> qb  bf16 [N_TOK][256]  (scale pre-folded)
// cols [256,768)-> kvb bf16 [N_TOK][512]
// ---------------------------------------------------------------------------
__global__ __launch_bounds__(256) void gemm_qkv(
    const __hip_bfloat16* __restrict__ A,
    const __hip_bfloat16* __restrict__ Bt,
    const float* __restrict__ bias,
    __hip_bfloat16* __restrict__ qb,
    __hip_bfloat16* __restrict__ kvb)
{
    __shared__ short Asm[2][128 * 32];
    __shared__ short Bsm[2][128 * 32];

    const int tid  = threadIdx.x;
    const int lane = tid & 63;
    const int wid  = tid >> 6;
    const int wr   = wid >> 1;
    const int wc   = wid & 1;
    const int bm   = blockIdx.y * 128;
    const int bn   = blockIdx.x * 128;

    f32x4 acc[4][4] = {};
    const int srow = lane >> 2;
    const int seg  = (((lane & 3) ^ (srow & 3)) << 3);

    auto stage = [&](int buf, int k0) {
        #pragma unroll
        for (int t = 0; t < 2; ++t) {
            int rbase = wid * 32 + t * 16;
            gload_lds16(A  + (size_t)(bm + rbase + srow) * 256 + k0 + seg, &Asm[buf][rbase * 32]);
            gload_lds16(Bt + (size_t)(bn + rbase + srow) * 256 + k0 + seg, &Bsm[buf][rbase * 32]);
        }
    };

    stage(0, 0);
    __syncthreads();
    const int csw = (((lane >> 4) ^ (lane & 3)) << 3);
    for (int kk = 0; kk < 8; ++kk) {
        const int cur = kk & 1;
        if (kk + 1 < 8) stage(cur ^ 1, (kk + 1) << 5);
        bf16x8 a[4], b[4];
        #pragma unroll
        for (int i = 0; i < 4; ++i)
            a[i] = *(const bf16x8*)&Asm[cur][(wr * 64 + i * 16 + (lane & 15)) * 32 + csw];
        #pragma unroll
        for (int j = 0; j < 4; ++j)
            b[j] = *(const bf16x8*)&Bsm[cur][(wc * 64 + j * 16 + (lane & 15)) * 32 + csw];
        #pragma unroll
        for (int i = 0; i < 4; ++i)
            #pragma unroll
            for (int j = 0; j < 4; ++j)
                acc[i][j] = __builtin_amdgcn_mfma_f32_16x16x32_bf16(a[i], b[j], acc[i][j], 0, 0, 0);
        __syncthreads();
    }

    const bool isq = (bn < 256);
    #pragma unroll
    for (int i = 0; i < 4; ++i) {
        int rbase = bm + wr * 64 + i * 16 + ((lane >> 4) << 2);
        #pragma unroll
        for (int j = 0; j < 4; ++j) {
            int col = bn + wc * 64 + j * 16 + (lane & 15);
            float bval = bias[col];
            #pragma unroll
            for (int r = 0; r < 4; ++r) {
                int row = rbase + r;
                float v = acc[i][j][r] + bval;
                if (isq) qb[(size_t)row * 256 + col] = __float2bfloat16(v);
                else     kvb[(size_t)row * 512 + (col - 256)] = __float2bfloat16(v);
            }
        }
    }
}

// ---------------------------------------------------------------------------
// ALL conversions in ONE dispatch (5377 blocks):
//   [0,4096)     src fp32 -> bf16 (1024 elems/block)
//   [4096,4288)  Wq|Wk|Wv -> WqkvT[768][256] (q scaled)
//   [4288,4352)  Wo -> WoT
//   [4352,4864)  W1 -> W1T
//   [4864,5376)  W2 -> W2T
//   5376         bqkv + key_start prefix sums
// ---------------------------------------------------------------------------
__global__ __launch_bounds__(256) void cvt_all(
    const float* __restrict__ src, __hip_bfloat16* __restrict__ src_bf,
    const float* __restrict__ Wq, const float* __restrict__ Wk,
    const float* __restrict__ Wv, const float* __restrict__ Wo,
    const float* __restrict__ W1, const float* __restrict__ W2,
    const float* __restrict__ bq, const float* __restrict__ bk,
    const float* __restrict__ bv, const int* __restrict__ kbc, int nb,
    __hip_bfloat16* __restrict__ WqkvT, __hip_bfloat16* __restrict__ WoT,
    __hip_bfloat16* __restrict__ W1T,   __hip_bfloat16* __restrict__ W2T,
    float* __restrict__ bqkv, int* __restrict__ ks, float qs)
{
    const int b = blockIdx.x;
    if (b < 4096) {                    // src f2b
        int i = (b * 256 + threadIdx.x) * 4;
        float4 v = *(const float4*)(src + i);
        short4 o;
        o.x = __builtin_bit_cast(short, __float2bfloat16(v.x));
        o.y = __builtin_bit_cast(short, __float2bfloat16(v.y));
        o.z = __builtin_bit_cast(short, __float2bfloat16(v.z));
        o.w = __builtin_bit_cast(short, __float2bfloat16(v.w));
        *(short4*)((short*)src_bf + i) = o;
        return;
    }
    if (b == 5376) {
        int i = threadIdx.x;
        #pragma unroll
        for (int t = 0; t < 3; ++t, i += 256) {
            if (i < 256)      bqkv[i] = bq[i] * qs;
            else if (i < 512) bqkv[i] = bk[i - 256];
            else              bqkv[i] = bv[i - 512];
        }
        i = threadIdx.x;
        if (i < nb) {
            int acc = 0;
            for (int j = 0; j < i; ++j) acc += kbc[j];
            ks[i] = acc;
        }
        return;
    }

    const int wb = b - 4096;
    const float* W; __hip_bfloat16* Wt; int N, ldo, n0, k0; float sc = 1.0f;
    if (wb < 192) {            // Wqkv
        n0 = (wb % 24) * 32; k0 = (wb / 24) * 32;
        N = 256; ldo = 256;
        W = (n0 < 256) ? Wq : (n0 < 512 ? Wk : Wv);
        sc = (n0 < 256) ? qs : 1.0f;
        Wt = WqkvT;
    } else if (wb < 256) {     // Wo
        int i = wb - 192; n0 = (i % 8) * 32; k0 = (i / 8) * 32;
        N = 256; ldo = 256; W = Wo; Wt = WoT;
    } else if (wb < 768) {     // W1
        int i = wb - 256; n0 = (i % 64) * 32; k0 = (i / 64) * 32;
        N = DFF; ldo = 256; W = W1; Wt = W1T;
    } else {                   // W2
        int i = wb - 768; n0 = (i % 8) * 32; k0 = (i / 8) * 32;
        N = 256; ldo = DFF; W = W2; Wt = W2T;
    }
    const int ncol = (wb < 192) ? (n0 & 255) : n0;

    __shared__ float t[32][33];
    const int tx = threadIdx.x & 31;
    const int ty = threadIdx.x >> 5;
    #pragma unroll
    for (int i = 0; i < 32; i += 8)
        t[ty + i][tx] = W[(size_t)(k0 + ty + i) * N + ncol + tx];
    __syncthreads();
    #pragma unroll
    for (int i = 0; i < 32; i += 8)
        Wt[(size_t)(n0 + ty + i) * ldo + k0 + tx] = __float2bfloat16(t[tx][ty + i] * sc);
}

// ---------------------------------------------------------------------------
// Gathered local attention: ONE WAVE per query, fully coalesced row gathers.
// q now bf16 (halves q traffic; K already bf16 so no accuracy cliff).
// ---------------------------------------------------------------------------
__global__ __launch_bounds__(256) void attn_wave(
    const __hip_bfloat16* __restrict__ qb,
    const __hip_bfloat16* __restrict__ kvb,
    const int* __restrict__ index_pair,
    const int* __restrict__ ipb,
    const int* __restrict__ key_start,
    __hip_bfloat16* __restrict__ out)
{
    const int w    = threadIdx.x >> 6;
    const int lane = threadIdx.x & 63;
    const int bid  = blockIdx.x;
    const int n  = (bid & 7) * 2048 + (bid >> 3) * 4 + w;
    const int c  = lane & 31;
    const int pp = lane >> 5;

    int raw = index_pair[(size_t)n * LNEIGH + c];
    int ks  = key_start[ipb[n]];
    int gi0 = (raw >= 0) ? raw + ks : -1;

    bf16x8 qv = *(const bf16x8*)(qb + (size_t)n * 256 + c * 8);
    float q[8];
    #pragma unroll
    for (int j = 0; j < 8; ++j) q[j] = b2f(qv[j]);

    int gi[16];
    #pragma unroll
    for (int i = 0; i < 16; ++i) gi[i] = __shfl(gi0, 2 * i + pp);

    bf16x8 kr[16];
    #pragma unroll
    for (int i = 0; i < 16; ++i) {
        int g = gi[i] < 0 ? 0 : gi[i];
        kr[i] = *(const bf16x8*)(kvb + (size_t)g * 512 + c * 8);
    }

    float s[16];
    #pragma unroll
    for (int i = 0; i < 16; ++i) {
        float t = q[0] * b2f(kr[i][0]) + q[1] * b2f(kr[i][1])
                + q[2] * b2f(kr[i][2]) + q[3] * b2f(kr[i][3])
                + q[4] * b2f(kr[i][4]) + q[5] * b2f(kr[i][5])
                + q[6] * b2f(kr[i][6]) + q[7] * b2f(kr[i][7]);
        t += __shfl_xor(t, 1);
        t += __shfl_xor(t, 2);
        s[i] = (gi[i] < 0) ? -1e9f : t;
    }

    bf16x8 vr[16];
    #pragma unroll
    for (int i = 0; i < 16; ++i) {
        int g = gi[i] < 0 ? 0 : gi[i];
        vr[i] = *(const bf16x8*)(kvb + (size_t)g * 512 + 256 + c * 8);
    }

    float m = s[0];
    #pragma unroll
    for (int i = 1; i < 16; ++i) m = fmaxf(m, s[i]);
    m = fmaxf(m, __shfl_xor(m, 32));
    float tot = 0.0f;
    #pragma unroll
    for (int i = 0; i < 16; ++i) { s[i] = __expf(s[i] - m); tot += s[i]; }
    tot += __shfl_xor(tot, 32);
    const float inv = 1.0f / tot;

    float a[8] = {};
    #pragma unroll
    for (int i = 0; i < 16; ++i) {
        float wt = s[i] * inv;
        #pragma unroll
        for (int j = 0; j < 8; ++j) a[j] += wt * b2f(vr[i][j]);
    }
    #pragma unroll
    for (int j = 0; j < 8; ++j) a[j] += __shfl_xor(a[j], 32);

    if (pp == 0) {
        bf16x8 ov;
        #pragma unroll
        for (int j = 0; j < 8; ++j)
            ov[j] = __builtin_bit_cast(short, __float2bfloat16(a[j]));
        *(bf16x8*)((short*)out + (size_t)n * 256 + c * 8) = ov;
    }
}

// ---------------------------------------------------------------------------
extern "C" void kernel_launch(void* const* d_in, const int* in_sizes, int n_in,
                              void* d_out, int out_size, void* d_ws, size_t ws_size,
                              hipStream_t stream)
{
    const float* src = (const float*)d_in[0];
    const int*   index_pair = (const int*)d_in[1];
    const int*   kbc = (const int*)d_in[3];
    const int*   ipb = (const int*)d_in[4];
    const float* Wq = (const float*)d_in[5];
    const float* bq = (const float*)d_in[6];
    const float* Wk = (const float*)d_in[7];
    const float* bk = (const float*)d_in[8];
    const float* Wv = (const float*)d_in[9];
    const float* bv = (const float*)d_in[10];
    const float* Wo = (const float*)d_in[11];
    const float* bo = (const float*)d_in[12];
    const float* W1 = (const float*)d_in[13];
    const float* b1 = (const float*)d_in[14];
    const float* W2 = (const float*)d_in[15];
    const float* b2 = (const float*)d_in[16];
    const float* g1 = (const float*)d_in[17];
    const float* be1 = (const float*)d_in[18];
    const float* g2 = (const float*)d_in[19];
    const float* be2 = (const float*)d_in[20];
    float* out = (float*)d_out;
    const int nb = in_sizes[3];

    char* ws = (char*)d_ws;
    const size_t O_SRCBF = 0;                        //  8.39 MB bf16 src
    const size_t O_QB    = 8388608;                  //  8.39 MB bf16 q
    const size_t O_KVB   = 25165824;                 // 16.78 MB bf16 k|v
    const size_t O_ATTN  = 41943040;                 //  8.39 MB bf16 attn out
    const size_t O_HC    = 0;                        // 64 MB alias (FFN hidden)
    const size_t O_XBF   = 67108864;                 //  8.39 MB bf16 x (LN1 out)
    const size_t O_WQKV  = 75497472;
    const size_t O_WO    = O_WQKV + 768 * 256 * 2;
    const size_t O_W1    = O_WO + 256 * 256 * 2;
    const size_t O_W2    = O_W1 + (size_t)DFF * 256 * 2;
    const size_t O_BQKV  = O_W2 + (size_t)DFF * 256 * 2;
    const size_t O_KS    = O_BQKV + 768 * 4;

    __hip_bfloat16* src_bf  = (__hip_bfloat16*)(ws + O_SRCBF);
    __hip_bfloat16* qb      = (__hip_bfloat16*)(ws + O_QB);
    __hip_bfloat16* kvb     = (__hip_bfloat16*)(ws + O_KVB);
    __hip_bfloat16* attn_bf = (__hip_bfloat16*)(ws + O_ATTN);
    __hip_bfloat16* hc      = (__hip_bfloat16*)(ws + O_HC);
    __hip_bfloat16* x_bf    = (__hip_bfloat16*)(ws + O_XBF);
    __hip_bfloat16* WqkvT   = (__hip_bfloat16*)(ws + O_WQKV);
    __hip_bfloat16* WoT     = (__hip_bfloat16*)(ws + O_WO);
    __hip_bfloat16* W1T     = (__hip_bfloat16*)(ws + O_W1);
    __hip_bfloat16* W2T     = (__hip_bfloat16*)(ws + O_W2);
    float*          bqkv    = (float*)(ws + O_BQKV);
    int*            ksbuf   = (int*)(ws + O_KS);

    const dim3 blk(256);
    const float qscale = 0.17677669529663687f;

    hipFuncSetAttribute(reinterpret_cast<const void*>(gemm_bk64_ln32),
                        hipFuncAttributeMaxDynamicSharedMemorySize, SMEM_LN32);

    // --- ALL conversions in one dispatch ---
    cvt_all<<<5377, blk, 0, stream>>>(src, src_bf, Wq, Wk, Wv, Wo, W1, W2,
                                      bq, bk, bv, kbc, nb,
                                      WqkvT, WoT, W1T, W2T, bqkv, ksbuf, qscale);

    // --- fused QKV projection: q -> bf16 qb, k|v -> bf16 kvb ---
    gemm_qkv<<<dim3(6, 128), blk, 0, stream>>>(src_bf, WqkvT, bqkv, qb, kvb);

    // --- gathered attention (wave per query, coalesced row gathers) ---
    attn_wave<<<dim3(N_TOK / 4), blk, 0, stream>>>(qb, kvb, index_pair, ipb, ksbuf, attn_bf);

    // --- Wo + residual(src) + LN1 fused -> x_bf ---
    gemm_bk64_ln32<<<dim3(N_TOK / 32), dim3(512), SMEM_LN32, stream>>>(
        attn_bf, 256, WoT, 256, bo, src, nullptr, g1, be1,
        nullptr, x_bf, 256);

    // --- FFN1 (N=2048, relu) -> hc ---
    gemm_bt<<<dim3(16, 128), blk, 0, stream>>>(
        x_bf, 256, W1T, 256, b1, hc, DFF, N_TOK, DFF, 256, 1);

    // --- FFN2 + residual(x_bf) + LN2 fused -> out ---
    gemm_bk64_ln32<<<dim3(N_TOK / 32), dim3(512), SMEM_LN32, stream>>>(
        hc, DFF, W2T, DFF, b2, nullptr, x_bf, g2, be2,
        out, nullptr, DFF);
}

// Round 19
// 137.433 us; speedup vs baseline: 1.5530x; 1.0340x over previous
//
#include <hip/hip_runtime.h>
#include <hip/hip_bf16.h>
#include <cstddef>
#include <cstdint>

#define D_MODEL 256
#define N_TOK   16384
#define NHEAD   8
#define HDIM    32
#define LNEIGH  32
#define DFF     2048

// dynamic LDS for gemm_bk64_ln32: A dbuf 8K + B dbuf 64K (LN scratch aliases A)
#define SMEM_LN32 (8192 + 65536)   // 73728 B -> 2 blocks/CU

typedef short bf16x8 __attribute__((ext_vector_type(8)));
typedef float f32x4  __attribute__((ext_vector_type(4)));

__device__ __forceinline__ float b2f(short s) {
    unsigned u = ((unsigned)(unsigned short)s) << 16;
    return __builtin_bit_cast(float, u);
}

// global -> LDS async copy, 16B per lane; LDS fills base + lane*16.
__device__ __forceinline__ void gload_lds16(const void* g, void* l) {
    auto* gp = reinterpret_cast<const __attribute__((address_space(1))) uint32_t*>(
        reinterpret_cast<uintptr_t>(g));
    auto* lp = reinterpret_cast<__attribute__((address_space(3))) uint32_t*>(
        reinterpret_cast<uintptr_t>(l));
    __builtin_amdgcn_global_load_lds(gp, lp, 16, 0, 0);
}

// ---------------------------------------------------------------------------
// bf16 MFMA GEMM, 128x128 tile, 4 waves, double-buffered K-loop, swizzled LDS.
// FLAT grid + XCD-chunked block swizzle: each XCD owns contiguous y-rows so
// the shared A-tile is fetched once to its L2 (T1 mechanism; shorter drains).
// C = A[M,K] @ Bt[N,K]^T. Epilogue: +bias, relu, bf16 out (pitch ldc).
// nbx = N/128 (x-blocks per row); grid.x = (M/128)*nbx, must be %8==0.
// ---------------------------------------------------------------------------
__global__ __launch_bounds__(256) void gemm_bt(
    const __hip_bfloat16* __restrict__ A, int lda,
    const __hip_bfloat16* __restrict__ Bt, int ldb,
    const float* __restrict__ bias,
    __hip_bfloat16* __restrict__ outb, int ldc,
    int M, int N, int K, int relu, int nbx)
{
    __shared__ short Asm[2][128 * 32];
    __shared__ short Bsm[2][128 * 32];

    // XCD-chunked swizzle (bijective: gridDim.x % 8 == 0)
    const int nwg  = gridDim.x;
    const int cpx  = nwg >> 3;
    const int lin  = (blockIdx.x & 7) * cpx + (blockIdx.x >> 3);
    const int by   = lin / nbx;
    const int bx   = lin - by * nbx;

    const int tid  = threadIdx.x;
    const int lane = tid & 63;
    const int wid  = tid >> 6;
    const int wr   = wid >> 1;
    const int wc   = wid & 1;
    const int bm   = by * 128;
    const int bn   = bx * 128;

    f32x4 acc[4][4] = {};
    const int srow = lane >> 2;
    const int seg  = (((lane & 3) ^ (srow & 3)) << 3);   // swizzled source chunk

    auto stage = [&](int buf, int k0) {
        #pragma unroll
        for (int t = 0; t < 2; ++t) {
            int rbase = wid * 32 + t * 16;
            gload_lds16(A  + (size_t)(bm + rbase + srow) * lda + k0 + seg, &Asm[buf][rbase * 32]);
            gload_lds16(Bt + (size_t)(bn + rbase + srow) * ldb + k0 + seg, &Bsm[buf][rbase * 32]);
        }
    };

    const int nk = K >> 5;
    stage(0, 0);
    __syncthreads();

    const int csw = (((lane >> 4) ^ (lane & 3)) << 3);   // swizzled read chunk

    for (int kk = 0; kk < nk; ++kk) {
        const int cur = kk & 1;
        if (kk + 1 < nk) stage(cur ^ 1, (kk + 1) << 5);

        bf16x8 a[4], b[4];
        #pragma unroll
        for (int i = 0; i < 4; ++i)
            a[i] = *(const bf16x8*)&Asm[cur][(wr * 64 + i * 16 + (lane & 15)) * 32 + csw];
        #pragma unroll
        for (int j = 0; j < 4; ++j)
            b[j] = *(const bf16x8*)&Bsm[cur][(wc * 64 + j * 16 + (lane & 15)) * 32 + csw];
        #pragma unroll
        for (int i = 0; i < 4; ++i)
            #pragma unroll
            for (int j = 0; j < 4; ++j)
                acc[i][j] = __builtin_amdgcn_mfma_f32_16x16x32_bf16(a[i], b[j], acc[i][j], 0, 0, 0);
        __syncthreads();
    }

    #pragma unroll
    for (int i = 0; i < 4; ++i) {
        int rbase = bm + wr * 64 + i * 16 + ((lane >> 4) << 2);
        #pragma unroll
        for (int j = 0; j < 4; ++j) {
            int col = bn + wc * 64 + j * 16 + (lane & 15);
            float bval = bias ? bias[col] : 0.0f;
            #pragma unroll
            for (int r = 0; r < 4; ++r) {
                int row = rbase + r;
                float v = acc[i][j][r] + bval;
                if (relu) v = fmaxf(v, 0.0f);
                outb[(size_t)row * ldc + col] = __float2bfloat16(v);
            }
        }
    }
}

// ---------------------------------------------------------------------------
// BK=64 LN-GEMM, BM=32: N=256, 8 waves (2x4), wave = 16x64. 72 KB dynamic LDS
// -> 2 blocks/CU (round-16 verified). Swizzle both sides -> 0 conflicts.
// LN scratch aliases the dead A buffer. Fused bias+residual+LayerNorm.
// ---------------------------------------------------------------------------
__global__ __launch_bounds__(512) void gemm_bk64_ln32(
    const __hip_bfloat16* __restrict__ A, int lda,
    const __hip_bfloat16* __restrict__ Bt, int ldb,
    const float* __restrict__ bias,
    const float* __restrict__ residf,
    const __hip_bfloat16* __restrict__ residb,
    const float* __restrict__ g,
    const float* __restrict__ be,
    float* __restrict__ outf,
    __hip_bfloat16* __restrict__ outb,
    int K)
{
    extern __shared__ char smem[];
    short* AsmB = (short*)smem;                      // [2][32*64]   8 KB
    short* BsmB = (short*)(smem + 8192);             // [2][256*64]  64 KB
    float* lnS  = (float*)smem;                      // aliases A (dead post-loop)
    float* lnS2 = (float*)(smem + 1024);
    float* rmu  = (float*)(smem + 2048);
    float* rrs  = (float*)(smem + 2176);

    const int tid  = threadIdx.x;
    const int lane = tid & 63;
    const int wid  = tid >> 6;
    const int wr   = wid >> 2;
    const int wc   = wid & 3;
    const int bm   = blockIdx.x * 32;
    const int lo   = lane & 15;
    const int hi   = lane >> 4;

    f32x4 acc[4] = {};

    const int srow8 = lane >> 3;
    const int sc    = lane & 7;
    const int ssw   = ((sc ^ srow8) << 3);

    auto stage = [&](int buf, int k0) {
        if (wid < 4)
            gload_lds16(A + (size_t)(bm + wid * 8 + srow8) * lda + k0 + ssw,
                        AsmB + buf * 2048 + (wid * 8) * 64);
        #pragma unroll
        for (int t = 0; t < 4; ++t) {
            int rb = wid * 32 + t * 8;
            gload_lds16(Bt + (size_t)(rb + srow8) * ldb + k0 + ssw,
                        BsmB + buf * 16384 + rb * 64);
        }
    };

    const int nk = K >> 6;
    stage(0, 0);
    __syncthreads();

    for (int kk = 0; kk < nk; ++kk) {
        const int cur = kk & 1;
        if (kk + 1 < nk) stage(cur ^ 1, (kk + 1) << 6);

        const short* Ab = AsmB + cur * 2048;
        const short* Bb = BsmB + cur * 16384;
        #pragma unroll
        for (int ks = 0; ks < 2; ++ks) {
            const int csw = ((ks * 4 + hi) ^ (lo & 7)) << 3;
            bf16x8 a = *(const bf16x8*)&Ab[(wr * 16 + lo) * 64 + csw];
            bf16x8 b[4];
            #pragma unroll
            for (int j = 0; j < 4; ++j)
                b[j] = *(const bf16x8*)&Bb[(wc * 64 + j * 16 + lo) * 64 + csw];
            #pragma unroll
            for (int j = 0; j < 4; ++j)
                acc[j] = __builtin_amdgcn_mfma_f32_16x16x32_bf16(a, b[j], acc[j], 0, 0, 0);
        }
        __syncthreads();
    }

    float ps[4] = {}, ps2[4] = {};
    #pragma unroll
    for (int j = 0; j < 4; ++j) {
        int col = wc * 64 + j * 16 + lo;
        float bval = bias ? bias[col] : 0.0f;
        #pragma unroll
        for (int r = 0; r < 4; ++r) {
            int row = bm + wr * 16 + hi * 4 + r;
            float v = acc[j][r] + bval;
            size_t o = (size_t)row * 256 + col;
            if (residf) v += residf[o];
            if (residb) v += __bfloat162float(residb[o]);
            acc[j][r] = v;
            ps[r]  += v;
            ps2[r] += v * v;
        }
    }
    #pragma unroll
    for (int r = 0; r < 4; ++r) {
        #pragma unroll
        for (int m = 1; m < 16; m <<= 1) {
            ps[r]  += __shfl_xor(ps[r],  m);
            ps2[r] += __shfl_xor(ps2[r], m);
        }
    }
    if (lo == 0) {
        #pragma unroll
        for (int r = 0; r < 4; ++r) {
            int rl = wr * 16 + hi * 4 + r;
            lnS[wid * 32 + rl]  = ps[r];
            lnS2[wid * 32 + rl] = ps2[r];
        }
    }
    __syncthreads();
    if (tid < 32) {
        int base = (tid >> 4) * 4;
        float s  = lnS[base * 32 + tid] + lnS[(base + 1) * 32 + tid]
                 + lnS[(base + 2) * 32 + tid] + lnS[(base + 3) * 32 + tid];
        float s2 = lnS2[base * 32 + tid] + lnS2[(base + 1) * 32 + tid]
                 + lnS2[(base + 2) * 32 + tid] + lnS2[(base + 3) * 32 + tid];
        float mu  = s * (1.0f / 256.0f);
        float var = s2 * (1.0f / 256.0f) - mu * mu;
        rmu[tid] = mu;
        rrs[tid] = rsqrtf(var + 1e-5f);
    }
    __syncthreads();

    #pragma unroll
    for (int j = 0; j < 4; ++j) {
        int col = wc * 64 + j * 16 + lo;
        float gg = g[col], bb = be[col];
        #pragma unroll
        for (int r = 0; r < 4; ++r) {
            int rl = wr * 16 + hi * 4 + r;
            float v = (acc[j][r] - rmu[rl]) * rrs[rl] * gg + bb;
            size_t o = (size_t)(bm + rl) * 256 + col;
            if (outf) outf[o] = v;
            if (outb) outb[o] = __float2bfloat16(v);
        }
    }
}

// ---------------------------------------------------------------------------
// QKV GEMM: flat grid + XCD-chunked swizzle (nbx=6). Split epilogue:
// cols [0,256) -> qb bf16 (scale pre-folded); cols [256,768) -> kvb bf16.
// ---------------------------------------------------------------------------
__global__ __launch_bounds__(256) void gemm_qkv(
    const __hip_bfloat16* __restrict__ A,
    const __hip_bfloat16* __restrict__ Bt,
    const float* __restrict__ bias,
    __hip_bfloat16* __restrict__ qb,
    __hip_bfloat16* __restrict__ kvb)
{
    __shared__ short Asm[2][128 * 32];
    __shared__ short Bsm[2][128 * 32];

    // grid.x = 768 (%8==0); 96 lin per XCD = 16 y-rows x 6 x-blocks
    const int cpx = gridDim.x >> 3;
    const int lin = (blockIdx.x & 7) * cpx + (blockIdx.x >> 3);
    const int by  = lin / 6;
    const int bx  = lin - by * 6;

    const int tid  = threadIdx.x;
    const int lane = tid & 63;
    const int wid  = tid >> 6;
    const int wr   = wid >> 1;
    const int wc   = wid & 1;
    const int bm   = by * 128;
    const int bn   = bx * 128;

    f32x4 acc[4][4] = {};
    const int srow = lane >> 2;
    const int seg  = (((lane & 3) ^ (srow & 3)) << 3);

    auto stage = [&](int buf, int k0) {
        #pragma unroll
        for (int t = 0; t < 2; ++t) {
            int rbase = wid * 32 + t * 16;
            gload_lds16(A  + (size_t)(bm + rbase + srow) * 256 + k0 + seg, &Asm[buf][rbase * 32]);
            gload_lds16(Bt + (size_t)(bn + rbase + srow) * 256 + k0 + seg, &Bsm[buf][rbase * 32]);
        }
    };

    stage(0, 0);
    __syncthreads();
    const int csw = (((lane >> 4) ^ (lane & 3)) << 3);
    for (int kk = 0; kk < 8; ++kk) {
        const int cur = kk & 1;
        if (kk + 1 < 8) stage(cur ^ 1, (kk + 1) << 5);
        bf16x8 a[4], b[4];
        #pragma unroll
        for (int i = 0; i < 4; ++i)
            a[i] = *(const bf16x8*)&Asm[cur][(wr * 64 + i * 16 + (lane & 15)) * 32 + csw];
        #pragma unroll
        for (int j = 0; j < 4; ++j)
            b[j] = *(const bf16x8*)&Bsm[cur][(wc * 64 + j * 16 + (lane & 15)) * 32 + csw];
        #pragma unroll
        for (int i = 0; i < 4; ++i)
            #pragma unroll
            for (int j = 0; j < 4; ++j)
                acc[i][j] = __builtin_amdgcn_mfma_f32_16x16x32_bf16(a[i], b[j], acc[i][j], 0, 0, 0);
        __syncthreads();
    }

    const bool isq = (bn < 256);
    #pragma unroll
    for (int i = 0; i < 4; ++i) {
        int rbase = bm + wr * 64 + i * 16 + ((lane >> 4) << 2);
        #pragma unroll
        for (int j = 0; j < 4; ++j) {
            int col = bn + wc * 64 + j * 16 + (lane & 15);
            float bval = bias[col];
            #pragma unroll
            for (int r = 0; r < 4; ++r) {
                int row = rbase + r;
                float v = acc[i][j][r] + bval;
                if (isq) qb[(size_t)row * 256 + col] = __float2bfloat16(v);
                else     kvb[(size_t)row * 512 + (col - 256)] = __float2bfloat16(v);
            }
        }
    }
}

// ---------------------------------------------------------------------------
// ALL conversions in ONE dispatch (5377 blocks).
// ---------------------------------------------------------------------------
__global__ __launch_bounds__(256) void cvt_all(
    const float* __restrict__ src, __hip_bfloat16* __restrict__ src_bf,
    const float* __restrict__ Wq, const float* __restrict__ Wk,
    const float* __restrict__ Wv, const float* __restrict__ Wo,
    const float* __restrict__ W1, const float* __restrict__ W2,
    const float* __restrict__ bq, const float* __restrict__ bk,
    const float* __restrict__ bv, const int* __restrict__ kbc, int nb,
    __hip_bfloat16* __restrict__ WqkvT, __hip_bfloat16* __restrict__ WoT,
    __hip_bfloat16* __restrict__ W1T,   __hip_bfloat16* __restrict__ W2T,
    float* __restrict__ bqkv, int* __restrict__ ks, float qs)
{
    const int b = blockIdx.x;
    if (b < 4096) {                    // src f2b
        int i = (b * 256 + threadIdx.x) * 4;
        float4 v = *(const float4*)(src + i);
        short4 o;
        o.x = __builtin_bit_cast(short, __float2bfloat16(v.x));
        o.y = __builtin_bit_cast(short, __float2bfloat16(v.y));
        o.z = __builtin_bit_cast(short, __float2bfloat16(v.z));
        o.w = __builtin_bit_cast(short, __float2bfloat16(v.w));
        *(short4*)((short*)src_bf + i) = o;
        return;
    }
    if (b == 5376) {
        int i = threadIdx.x;
        #pragma unroll
        for (int t = 0; t < 3; ++t, i += 256) {
            if (i < 256)      bqkv[i] = bq[i] * qs;
            else if (i < 512) bqkv[i] = bk[i - 256];
            else              bqkv[i] = bv[i - 512];
        }
        i = threadIdx.x;
        if (i < nb) {
            int acc = 0;
            for (int j = 0; j < i; ++j) acc += kbc[j];
            ks[i] = acc;
        }
        return;
    }

    const int wb = b - 4096;
    const float* W; __hip_bfloat16* Wt; int N, ldo, n0, k0; float sc = 1.0f;
    if (wb < 192) {
        n0 = (wb % 24) * 32; k0 = (wb / 24) * 32;
        N = 256; ldo = 256;
        W = (n0 < 256) ? Wq : (n0 < 512 ? Wk : Wv);
        sc = (n0 < 256) ? qs : 1.0f;
        Wt = WqkvT;
    } else if (wb < 256) {
        int i = wb - 192; n0 = (i % 8) * 32; k0 = (i / 8) * 32;
        N = 256; ldo = 256; W = Wo; Wt = WoT;
    } else if (wb < 768) {
        int i = wb - 256; n0 = (i % 64) * 32; k0 = (i / 64) * 32;
        N = DFF; ldo = 256; W = W1; Wt = W1T;
    } else {
        int i = wb - 768; n0 = (i % 8) * 32; k0 = (i / 8) * 32;
        N = 256; ldo = DFF; W = W2; Wt = W2T;
    }
    const int ncol = (wb < 192) ? (n0 & 255) : n0;

    __shared__ float t[32][33];
    const int tx = threadIdx.x & 31;
    const int ty = threadIdx.x >> 5;
    #pragma unroll
    for (int i = 0; i < 32; i += 8)
        t[ty + i][tx] = W[(size_t)(k0 + ty + i) * N + ncol + tx];
    __syncthreads();
    #pragma unroll
    for (int i = 0; i < 32; i += 8)
        Wt[(size_t)(n0 + ty + i) * ldo + k0 + tx] = __float2bfloat16(t[tx][ty + i] * sc);
}

// ---------------------------------------------------------------------------
// Gathered local attention: ONE WAVE per query, fully coalesced row gathers.
// ---------------------------------------------------------------------------
__global__ __launch_bounds__(256) void attn_wave(
    const __hip_bfloat16* __restrict__ qb,
    const __hip_bfloat16* __restrict__ kvb,
    const int* __restrict__ index_pair,
    const int* __restrict__ ipb,
    const int* __restrict__ key_start,
    __hip_bfloat16* __restrict__ out)
{
    const int w    = threadIdx.x >> 6;
    const int lane = threadIdx.x & 63;
    const int bid  = blockIdx.x;
    const int n  = (bid & 7) * 2048 + (bid >> 3) * 4 + w;
    const int c  = lane & 31;
    const int pp = lane >> 5;

    int raw = index_pair[(size_t)n * LNEIGH + c];
    int ks  = key_start[ipb[n]];
    int gi0 = (raw >= 0) ? raw + ks : -1;

    bf16x8 qv = *(const bf16x8*)(qb + (size_t)n * 256 + c * 8);
    float q[8];
    #pragma unroll
    for (int j = 0; j < 8; ++j) q[j] = b2f(qv[j]);

    int gi[16];
    #pragma unroll
    for (int i = 0; i < 16; ++i) gi[i] = __shfl(gi0, 2 * i + pp);

    bf16x8 kr[16];
    #pragma unroll
    for (int i = 0; i < 16; ++i) {
        int g = gi[i] < 0 ? 0 : gi[i];
        kr[i] = *(const bf16x8*)(kvb + (size_t)g * 512 + c * 8);
    }

    float s[16];
    #pragma unroll
    for (int i = 0; i < 16; ++i) {
        float t = q[0] * b2f(kr[i][0]) + q[1] * b2f(kr[i][1])
                + q[2] * b2f(kr[i][2]) + q[3] * b2f(kr[i][3])
                + q[4] * b2f(kr[i][4]) + q[5] * b2f(kr[i][5])
                + q[6] * b2f(kr[i][6]) + q[7] * b2f(kr[i][7]);
        t += __shfl_xor(t, 1);
        t += __shfl_xor(t, 2);
        s[i] = (gi[i] < 0) ? -1e9f : t;
    }

    bf16x8 vr[16];
    #pragma unroll
    for (int i = 0; i < 16; ++i) {
        int g = gi[i] < 0 ? 0 : gi[i];
        vr[i] = *(const bf16x8*)(kvb + (size_t)g * 512 + 256 + c * 8);
    }

    float m = s[0];
    #pragma unroll
    for (int i = 1; i < 16; ++i) m = fmaxf(m, s[i]);
    m = fmaxf(m, __shfl_xor(m, 32));
    float tot = 0.0f;
    #pragma unroll
    for (int i = 0; i < 16; ++i) { s[i] = __expf(s[i] - m); tot += s[i]; }
    tot += __shfl_xor(tot, 32);
    const float inv = 1.0f / tot;

    float a[8] = {};
    #pragma unroll
    for (int i = 0; i < 16; ++i) {
        float wt = s[i] * inv;
        #pragma unroll
        for (int j = 0; j < 8; ++j) a[j] += wt * b2f(vr[i][j]);
    }
    #pragma unroll
    for (int j = 0; j < 8; ++j) a[j] += __shfl_xor(a[j], 32);

    if (pp == 0) {
        bf16x8 ov;
        #pragma unroll
        for (int j = 0; j < 8; ++j)
            ov[j] = __builtin_bit_cast(short, __float2bfloat16(a[j]));
        *(bf16x8*)((short*)out + (size_t)n * 256 + c * 8) = ov;
    }
}

// ---------------------------------------------------------------------------
extern "C" void kernel_launch(void* const* d_in, const int* in_sizes, int n_in,
                              void* d_out, int out_size, void* d_ws, size_t ws_size,
                              hipStream_t stream)
{
    const float* src = (const float*)d_in[0];
    const int*   index_pair = (const int*)d_in[1];
    const int*   kbc = (const int*)d_in[3];
    const int*   ipb = (const int*)d_in[4];
    const float* Wq = (const float*)d_in[5];
    const float* bq = (const float*)d_in[6];
    const float* Wk = (const float*)d_in[7];
    const float* bk = (const float*)d_in[8];
    const float* Wv = (const float*)d_in[9];
    const float* bv = (const float*)d_in[10];
    const float* Wo = (const float*)d_in[11];
    const float* bo = (const float*)d_in[12];
    const float* W1 = (const float*)d_in[13];
    const float* b1 = (const float*)d_in[14];
    const float* W2 = (const float*)d_in[15];
    const float* b2 = (const float*)d_in[16];
    const float* g1 = (const float*)d_in[17];
    const float* be1 = (const float*)d_in[18];
    const float* g2 = (const float*)d_in[19];
    const float* be2 = (const float*)d_in[20];
    float* out = (float*)d_out;
    const int nb = in_sizes[3];

    char* ws = (char*)d_ws;
    const size_t O_SRCBF = 0;                        //  8.39 MB bf16 src
    const size_t O_QB    = 8388608;                  //  8.39 MB bf16 q
    const size_t O_KVB   = 25165824;                 // 16.78 MB bf16 k|v
    const size_t O_ATTN  = 41943040;                 //  8.39 MB bf16 attn out
    const size_t O_HC    = 0;                        // 64 MB alias (FFN hidden)
    const size_t O_XBF   = 67108864;                 //  8.39 MB bf16 x (LN1 out)
    const size_t O_WQKV  = 75497472;
    const size_t O_WO    = O_WQKV + 768 * 256 * 2;
    const size_t O_W1    = O_WO + 256 * 256 * 2;
    const size_t O_W2    = O_W1 + (size_t)DFF * 256 * 2;
    const size_t O_BQKV  = O_W2 + (size_t)DFF * 256 * 2;
    const size_t O_KS    = O_BQKV + 768 * 4;

    __hip_bfloat16* src_bf  = (__hip_bfloat16*)(ws + O_SRCBF);
    __hip_bfloat16* qb      = (__hip_bfloat16*)(ws + O_QB);
    __hip_bfloat16* kvb     = (__hip_bfloat16*)(ws + O_KVB);
    __hip_bfloat16* attn_bf = (__hip_bfloat16*)(ws + O_ATTN);
    __hip_bfloat16* hc      = (__hip_bfloat16*)(ws + O_HC);
    __hip_bfloat16* x_bf    = (__hip_bfloat16*)(ws + O_XBF);
    __hip_bfloat16* WqkvT   = (__hip_bfloat16*)(ws + O_WQKV);
    __hip_bfloat16* WoT     = (__hip_bfloat16*)(ws + O_WO);
    __hip_bfloat16* W1T     = (__hip_bfloat16*)(ws + O_W1);
    __hip_bfloat16* W2T     = (__hip_bfloat16*)(ws + O_W2);
    float*          bqkv    = (float*)(ws + O_BQKV);
    int*            ksbuf   = (int*)(ws + O_KS);

    const dim3 blk(256);
    const float qscale = 0.17677669529663687f;

    hipFuncSetAttribute(reinterpret_cast<const void*>(gemm_bk64_ln32),
                        hipFuncAttributeMaxDynamicSharedMemorySize, SMEM_LN32);

    // --- ALL conversions in one dispatch ---
    cvt_all<<<5377, blk, 0, stream>>>(src, src_bf, Wq, Wk, Wv, Wo, W1, W2,
                                      bq, bk, bv, kbc, nb,
                                      WqkvT, WoT, W1T, W2T, bqkv, ksbuf, qscale);

    // --- fused QKV projection (flat 768-block grid, XCD-swizzled) ---
    gemm_qkv<<<768, blk, 0, stream>>>(src_bf, WqkvT, bqkv, qb, kvb);

    // --- gathered attention (wave per query, coalesced row gathers) ---
    attn_wave<<<dim3(N_TOK / 4), blk, 0, stream>>>(qb, kvb, index_pair, ipb, ksbuf, attn_bf);

    // --- Wo + residual(src) + LN1 fused -> x_bf ---
    gemm_bk64_ln32<<<dim3(N_TOK / 32), dim3(512), SMEM_LN32, stream>>>(
        attn_bf, 256, WoT, 256, bo, src, nullptr, g1, be1,
        nullptr, x_bf, 256);

    // --- FFN1 (N=2048, relu) -> hc (flat 2048-block grid, XCD-swizzled) ---
    gemm_bt<<<2048, blk, 0, stream>>>(
        x_bf, 256, W1T, 256, b1, hc, DFF, N_TOK, DFF, 256, 1, 16);

    // --- FFN2 + residual(x_bf) + LN2 fused -> out ---
    gemm_bk64_ln32<<<dim3(N_TOK / 32), dim3(512), SMEM_LN32, stream>>>(
        hc, DFF, W2T, DFF, b2, nullptr, x_bf, g2, be2,
        out, nullptr, DFF);
}

// Round 20
// 136.833 us; speedup vs baseline: 1.5598x; 1.0044x over previous
//
#include <hip/hip_runtime.h>
#include <hip/hip_bf16.h>
#include <cstddef>
#include <cstdint>

#define D_MODEL 256
#define N_TOK   16384
#define NHEAD   8
#define HDIM    32
#define LNEIGH  32
#define DFF     2048

// dynamic LDS for gemm_bk64_ln32: A dbuf 8K + B dbuf 64K (LN scratch aliases A)
#define SMEM_LN32 (8192 + 65536)   // 73728 B -> 2 blocks/CU

typedef short    bf16x8 __attribute__((ext_vector_type(8)));
typedef float    f32x4  __attribute__((ext_vector_type(4)));
typedef _Float16 h16x8  __attribute__((ext_vector_type(8)));
typedef _Float16 h16x2  __attribute__((ext_vector_type(2)));

__device__ __forceinline__ float b2f(short s) {
    unsigned u = ((unsigned)(unsigned short)s) << 16;
    return __builtin_bit_cast(float, u);
}

// global -> LDS async copy, 16B per lane; LDS fills base + lane*16.
__device__ __forceinline__ void gload_lds16(const void* g, void* l) {
    auto* gp = reinterpret_cast<const __attribute__((address_space(1))) uint32_t*>(
        reinterpret_cast<uintptr_t>(g));
    auto* lp = reinterpret_cast<__attribute__((address_space(3))) uint32_t*>(
        reinterpret_cast<uintptr_t>(l));
    __builtin_amdgcn_global_load_lds(gp, lp, 16, 0, 0);
}

// ---------------------------------------------------------------------------
// bf16 MFMA GEMM, 128x128 tile, 4 waves, double-buffered K-loop, swizzled LDS.
// FLAT grid + XCD-chunked block swizzle (round-19 verified: -4.7 us).
// C = A[M,K] @ Bt[N,K]^T. Epilogue: +bias, relu, bf16 out (pitch ldc).
// ---------------------------------------------------------------------------
__global__ __launch_bounds__(256) void gemm_bt(
    const __hip_bfloat16* __restrict__ A, int lda,
    const __hip_bfloat16* __restrict__ Bt, int ldb,
    const float* __restrict__ bias,
    __hip_bfloat16* __restrict__ outb, int ldc,
    int M, int N, int K, int relu, int nbx)
{
    __shared__ short Asm[2][128 * 32];
    __shared__ short Bsm[2][128 * 32];

    const int nwg  = gridDim.x;
    const int cpx  = nwg >> 3;
    const int lin  = (blockIdx.x & 7) * cpx + (blockIdx.x >> 3);
    const int by   = lin / nbx;
    const int bx   = lin - by * nbx;

    const int tid  = threadIdx.x;
    const int lane = tid & 63;
    const int wid  = tid >> 6;
    const int wr   = wid >> 1;
    const int wc   = wid & 1;
    const int bm   = by * 128;
    const int bn   = bx * 128;

    f32x4 acc[4][4] = {};
    const int srow = lane >> 2;
    const int seg  = (((lane & 3) ^ (srow & 3)) << 3);   // swizzled source chunk

    auto stage = [&](int buf, int k0) {
        #pragma unroll
        for (int t = 0; t < 2; ++t) {
            int rbase = wid * 32 + t * 16;
            gload_lds16(A  + (size_t)(bm + rbase + srow) * lda + k0 + seg, &Asm[buf][rbase * 32]);
            gload_lds16(Bt + (size_t)(bn + rbase + srow) * ldb + k0 + seg, &Bsm[buf][rbase * 32]);
        }
    };

    const int nk = K >> 5;
    stage(0, 0);
    __syncthreads();

    const int csw = (((lane >> 4) ^ (lane & 3)) << 3);   // swizzled read chunk

    for (int kk = 0; kk < nk; ++kk) {
        const int cur = kk & 1;
        if (kk + 1 < nk) stage(cur ^ 1, (kk + 1) << 5);

        bf16x8 a[4], b[4];
        #pragma unroll
        for (int i = 0; i < 4; ++i)
            a[i] = *(const bf16x8*)&Asm[cur][(wr * 64 + i * 16 + (lane & 15)) * 32 + csw];
        #pragma unroll
        for (int j = 0; j < 4; ++j)
            b[j] = *(const bf16x8*)&Bsm[cur][(wc * 64 + j * 16 + (lane & 15)) * 32 + csw];
        #pragma unroll
        for (int i = 0; i < 4; ++i)
            #pragma unroll
            for (int j = 0; j < 4; ++j)
                acc[i][j] = __builtin_amdgcn_mfma_f32_16x16x32_bf16(a[i], b[j], acc[i][j], 0, 0, 0);
        __syncthreads();
    }

    #pragma unroll
    for (int i = 0; i < 4; ++i) {
        int rbase = bm + wr * 64 + i * 16 + ((lane >> 4) << 2);
        #pragma unroll
        for (int j = 0; j < 4; ++j) {
            int col = bn + wc * 64 + j * 16 + (lane & 15);
            float bval = bias ? bias[col] : 0.0f;
            #pragma unroll
            for (int r = 0; r < 4; ++r) {
                int row = rbase + r;
                float v = acc[i][j][r] + bval;
                if (relu) v = fmaxf(v, 0.0f);
                outb[(size_t)row * ldc + col] = __float2bfloat16(v);
            }
        }
    }
}

// ---------------------------------------------------------------------------
// BK=64 LN-GEMM, BM=32: N=256, 8 waves (2x4), wave = 16x64. 72 KB dynamic LDS
// -> 2 blocks/CU. Swizzle both sides -> 0 conflicts (round-14/16 verified).
// LN scratch aliases the dead A buffer. Fused bias+residual+LayerNorm.
// ---------------------------------------------------------------------------
__global__ __launch_bounds__(512) void gemm_bk64_ln32(
    const __hip_bfloat16* __restrict__ A, int lda,
    const __hip_bfloat16* __restrict__ Bt, int ldb,
    const float* __restrict__ bias,
    const float* __restrict__ residf,
    const __hip_bfloat16* __restrict__ residb,
    const float* __restrict__ g,
    const float* __restrict__ be,
    float* __restrict__ outf,
    __hip_bfloat16* __restrict__ outb,
    int K)
{
    extern __shared__ char smem[];
    short* AsmB = (short*)smem;                      // [2][32*64]   8 KB
    short* BsmB = (short*)(smem + 8192);             // [2][256*64]  64 KB
    float* lnS  = (float*)smem;                      // aliases A (dead post-loop)
    float* lnS2 = (float*)(smem + 1024);
    float* rmu  = (float*)(smem + 2048);
    float* rrs  = (float*)(smem + 2176);

    const int tid  = threadIdx.x;
    const int lane = tid & 63;
    const int wid  = tid >> 6;
    const int wr   = wid >> 2;
    const int wc   = wid & 3;
    const int bm   = blockIdx.x * 32;
    const int lo   = lane & 15;
    const int hi   = lane >> 4;

    f32x4 acc[4] = {};

    const int srow8 = lane >> 3;
    const int sc    = lane & 7;
    const int ssw   = ((sc ^ srow8) << 3);

    auto stage = [&](int buf, int k0) {
        if (wid < 4)
            gload_lds16(A + (size_t)(bm + wid * 8 + srow8) * lda + k0 + ssw,
                        AsmB + buf * 2048 + (wid * 8) * 64);
        #pragma unroll
        for (int t = 0; t < 4; ++t) {
            int rb = wid * 32 + t * 8;
            gload_lds16(Bt + (size_t)(rb + srow8) * ldb + k0 + ssw,
                        BsmB + buf * 16384 + rb * 64);
        }
    };

    const int nk = K >> 6;
    stage(0, 0);
    __syncthreads();

    for (int kk = 0; kk < nk; ++kk) {
        const int cur = kk & 1;
        if (kk + 1 < nk) stage(cur ^ 1, (kk + 1) << 6);

        const short* Ab = AsmB + cur * 2048;
        const short* Bb = BsmB + cur * 16384;
        #pragma unroll
        for (int ks = 0; ks < 2; ++ks) {
            const int csw = ((ks * 4 + hi) ^ (lo & 7)) << 3;
            bf16x8 a = *(const bf16x8*)&Ab[(wr * 16 + lo) * 64 + csw];
            bf16x8 b[4];
            #pragma unroll
            for (int j = 0; j < 4; ++j)
                b[j] = *(const bf16x8*)&Bb[(wc * 64 + j * 16 + lo) * 64 + csw];
            #pragma unroll
            for (int j = 0; j < 4; ++j)
                acc[j] = __builtin_amdgcn_mfma_f32_16x16x32_bf16(a, b[j], acc[j], 0, 0, 0);
        }
        __syncthreads();
    }

    float ps[4] = {}, ps2[4] = {};
    #pragma unroll
    for (int j = 0; j < 4; ++j) {
        int col = wc * 64 + j * 16 + lo;
        float bval = bias ? bias[col] : 0.0f;
        #pragma unroll
        for (int r = 0; r < 4; ++r) {
            int row = bm + wr * 16 + hi * 4 + r;
            float v = acc[j][r] + bval;
            size_t o = (size_t)row * 256 + col;
            if (residf) v += residf[o];
            if (residb) v += __bfloat162float(residb[o]);
            acc[j][r] = v;
            ps[r]  += v;
            ps2[r] += v * v;
        }
    }
    #pragma unroll
    for (int r = 0; r < 4; ++r) {
        #pragma unroll
        for (int m = 1; m < 16; m <<= 1) {
            ps[r]  += __shfl_xor(ps[r],  m);
            ps2[r] += __shfl_xor(ps2[r], m);
        }
    }
    if (lo == 0) {
        #pragma unroll
        for (int r = 0; r < 4; ++r) {
            int rl = wr * 16 + hi * 4 + r;
            lnS[wid * 32 + rl]  = ps[r];
            lnS2[wid * 32 + rl] = ps2[r];
        }
    }
    __syncthreads();
    if (tid < 32) {
        int base = (tid >> 4) * 4;
        float s  = lnS[base * 32 + tid] + lnS[(base + 1) * 32 + tid]
                 + lnS[(base + 2) * 32 + tid] + lnS[(base + 3) * 32 + tid];
        float s2 = lnS2[base * 32 + tid] + lnS2[(base + 1) * 32 + tid]
                 + lnS2[(base + 2) * 32 + tid] + lnS2[(base + 3) * 32 + tid];
        float mu  = s * (1.0f / 256.0f);
        float var = s2 * (1.0f / 256.0f) - mu * mu;
        rmu[tid] = mu;
        rrs[tid] = rsqrtf(var + 1e-5f);
    }
    __syncthreads();

    #pragma unroll
    for (int j = 0; j < 4; ++j) {
        int col = wc * 64 + j * 16 + lo;
        float gg = g[col], bb = be[col];
        #pragma unroll
        for (int r = 0; r < 4; ++r) {
            int rl = wr * 16 + hi * 4 + r;
            float v = (acc[j][r] - rmu[rl]) * rrs[rl] * gg + bb;
            size_t o = (size_t)(bm + rl) * 256 + col;
            if (outf) outf[o] = v;
            if (outb) outb[o] = __float2bfloat16(v);
        }
    }
}

// ---------------------------------------------------------------------------
// QKV GEMM: flat grid + XCD-chunked swizzle (nbx=6). Split epilogue:
// cols [0,256) -> qh fp16 (scale pre-folded); cols [256,768) -> kvh fp16.
// (fp16 enables v_dot2_f32_f16 in attention; e5m10 > bf16 precision here.)
// ---------------------------------------------------------------------------
__global__ __launch_bounds__(256) void gemm_qkv(
    const __hip_bfloat16* __restrict__ A,
    const __hip_bfloat16* __restrict__ Bt,
    const float* __restrict__ bias,
    _Float16* __restrict__ qh,
    _Float16* __restrict__ kvh)
{
    __shared__ short Asm[2][128 * 32];
    __shared__ short Bsm[2][128 * 32];

    const int cpx = gridDim.x >> 3;
    const int lin = (blockIdx.x & 7) * cpx + (blockIdx.x >> 3);
    const int by  = lin / 6;
    const int bx  = lin - by * 6;

    const int tid  = threadIdx.x;
    const int lane = tid & 63;
    const int wid  = tid >> 6;
    const int wr   = wid >> 1;
    const int wc   = wid & 1;
    const int bm   = by * 128;
    const int bn   = bx * 128;

    f32x4 acc[4][4] = {};
    const int srow = lane >> 2;
    const int seg  = (((lane & 3) ^ (srow & 3)) << 3);

    auto stage = [&](int buf, int k0) {
        #pragma unroll
        for (int t = 0; t < 2; ++t) {
            int rbase = wid * 32 + t * 16;
            gload_lds16(A  + (size_t)(bm + rbase + srow) * 256 + k0 + seg, &Asm[buf][rbase * 32]);
            gload_lds16(Bt + (size_t)(bn + rbase + srow) * 256 + k0 + seg, &Bsm[buf][rbase * 32]);
        }
    };

    stage(0, 0);
    __syncthreads();
    const int csw = (((lane >> 4) ^ (lane & 3)) << 3);
    for (int kk = 0; kk < 8; ++kk) {
        const int cur = kk & 1;
        if (kk + 1 < 8) stage(cur ^ 1, (kk + 1) << 5);
        bf16x8 a[4], b[4];
        #pragma unroll
        for (int i = 0; i < 4; ++i)
            a[i] = *(const bf16x8*)&Asm[cur][(wr * 64 + i * 16 + (lane & 15)) * 32 + csw];
        #pragma unroll
        for (int j = 0; j < 4; ++j)
            b[j] = *(const bf16x8*)&Bsm[cur][(wc * 64 + j * 16 + (lane & 15)) * 32 + csw];
        #pragma unroll
        for (int i = 0; i < 4; ++i)
            #pragma unroll
            for (int j = 0; j < 4; ++j)
                acc[i][j] = __builtin_amdgcn_mfma_f32_16x16x32_bf16(a[i], b[j], acc[i][j], 0, 0, 0);
        __syncthreads();
    }

    const bool isq = (bn < 256);
    #pragma unroll
    for (int i = 0; i < 4; ++i) {
        int rbase = bm + wr * 64 + i * 16 + ((lane >> 4) << 2);
        #pragma unroll
        for (int j = 0; j < 4; ++j) {
            int col = bn + wc * 64 + j * 16 + (lane & 15);
            float bval = bias[col];
            #pragma unroll
            for (int r = 0; r < 4; ++r) {
                int row = rbase + r;
                float v = acc[i][j][r] + bval;
                if (isq) qh[(size_t)row * 256 + col] = (_Float16)v;
                else     kvh[(size_t)row * 512 + (col - 256)] = (_Float16)v;
            }
        }
    }
}

// ---------------------------------------------------------------------------
// ALL conversions in ONE dispatch (5377 blocks).
// ---------------------------------------------------------------------------
__global__ __launch_bounds__(256) void cvt_all(
    const float* __restrict__ src, __hip_bfloat16* __restrict__ src_bf,
    const float* __restrict__ Wq, const float* __restrict__ Wk,
    const float* __restrict__ Wv, const float* __restrict__ Wo,
    const float* __restrict__ W1, const float* __restrict__ W2,
    const float* __restrict__ bq, const float* __restrict__ bk,
    const float* __restrict__ bv, const int* __restrict__ kbc, int nb,
    __hip_bfloat16* __restrict__ WqkvT, __hip_bfloat16* __restrict__ WoT,
    __hip_bfloat16* __restrict__ W1T,   __hip_bfloat16* __restrict__ W2T,
    float* __restrict__ bqkv, int* __restrict__ ks, float qs)
{
    const int b = blockIdx.x;
    if (b < 4096) {                    // src f2b
        int i = (b * 256 + threadIdx.x) * 4;
        float4 v = *(const float4*)(src + i);
        short4 o;
        o.x = __builtin_bit_cast(short, __float2bfloat16(v.x));
        o.y = __builtin_bit_cast(short, __float2bfloat16(v.y));
        o.z = __builtin_bit_cast(short, __float2bfloat16(v.z));
        o.w = __builtin_bit_cast(short, __float2bfloat16(v.w));
        *(short4*)((short*)src_bf + i) = o;
        return;
    }
    if (b == 5376) {
        int i = threadIdx.x;
        #pragma unroll
        for (int t = 0; t < 3; ++t, i += 256) {
            if (i < 256)      bqkv[i] = bq[i] * qs;
            else if (i < 512) bqkv[i] = bk[i - 256];
            else              bqkv[i] = bv[i - 512];
        }
        i = threadIdx.x;
        if (i < nb) {
            int acc = 0;
            for (int j = 0; j < i; ++j) acc += kbc[j];
            ks[i] = acc;
        }
        return;
    }

    const int wb = b - 4096;
    const float* W; __hip_bfloat16* Wt; int N, ldo, n0, k0; float sc = 1.0f;
    if (wb < 192) {
        n0 = (wb % 24) * 32; k0 = (wb / 24) * 32;
        N = 256; ldo = 256;
        W = (n0 < 256) ? Wq : (n0 < 512 ? Wk : Wv);
        sc = (n0 < 256) ? qs : 1.0f;
        Wt = WqkvT;
    } else if (wb < 256) {
        int i = wb - 192; n0 = (i % 8) * 32; k0 = (i / 8) * 32;
        N = 256; ldo = 256; W = Wo; Wt = WoT;
    } else if (wb < 768) {
        int i = wb - 256; n0 = (i % 64) * 32; k0 = (i / 64) * 32;
        N = DFF; ldo = 256; W = W1; Wt = W1T;
    } else {
        int i = wb - 768; n0 = (i % 8) * 32; k0 = (i / 8) * 32;
        N = 256; ldo = DFF; W = W2; Wt = W2T;
    }
    const int ncol = (wb < 192) ? (n0 & 255) : n0;

    __shared__ float t[32][33];
    const int tx = threadIdx.x & 31;
    const int ty = threadIdx.x >> 5;
    #pragma unroll
    for (int i = 0; i < 32; i += 8)
        t[ty + i][tx] = W[(size_t)(k0 + ty + i) * N + ncol + tx];
    __syncthreads();
    #pragma unroll
    for (int i = 0; i < 32; i += 8)
        Wt[(size_t)(n0 + ty + i) * ldo + k0 + tx] = __float2bfloat16(t[tx][ty + i] * sc);
}

// ---------------------------------------------------------------------------
// Gathered local attention: ONE WAVE per query, coalesced row gathers, fp16
// q/k/v with v_dot2_f32_f16 QK (4 instr per 8 elems vs 16 for bf16 unpack).
// ---------------------------------------------------------------------------
__global__ __launch_bounds__(256) void attn_wave(
    const _Float16* __restrict__ qh,
    const _Float16* __restrict__ kvh,
    const int* __restrict__ index_pair,
    const int* __restrict__ ipb,
    const int* __restrict__ key_start,
    __hip_bfloat16* __restrict__ out)
{
    const int w    = threadIdx.x >> 6;
    const int lane = threadIdx.x & 63;
    const int bid  = blockIdx.x;
    const int n  = (bid & 7) * 2048 + (bid >> 3) * 4 + w;  // XCD swizzle
    const int c  = lane & 31;      // dim chunk: dims [c*8, c*8+8)
    const int pp = lane >> 5;      // row parity

    int raw = index_pair[(size_t)n * LNEIGH + c];
    int ks  = key_start[ipb[n]];
    int gi0 = (raw >= 0) ? raw + ks : -1;

    const h16x8 qv = *(const h16x8*)(qh + (size_t)n * 256 + c * 8);
    h16x2 q2[4];
    #pragma unroll
    for (int u = 0; u < 4; ++u) { q2[u][0] = qv[2 * u]; q2[u][1] = qv[2 * u + 1]; }

    int gi[16];
    #pragma unroll
    for (int i = 0; i < 16; ++i) gi[i] = __shfl(gi0, 2 * i + pp);

    h16x8 kr[16];
    #pragma unroll
    for (int i = 0; i < 16; ++i) {
        int g = gi[i] < 0 ? 0 : gi[i];
        kr[i] = *(const h16x8*)(kvh + (size_t)g * 512 + c * 8);
    }

    float s[16];
    #pragma unroll
    for (int i = 0; i < 16; ++i) {
        float t = 0.0f;
        #pragma unroll
        for (int u = 0; u < 4; ++u) {
            h16x2 k2; k2[0] = kr[i][2 * u]; k2[1] = kr[i][2 * u + 1];
            t = __builtin_amdgcn_fdot2(q2[u], k2, t, false);
        }
        t += __shfl_xor(t, 1);
        t += __shfl_xor(t, 2);
        s[i] = (gi[i] < 0) ? -1e9f : t;
    }

    h16x8 vr[16];
    #pragma unroll
    for (int i = 0; i < 16; ++i) {
        int g = gi[i] < 0 ? 0 : gi[i];
        vr[i] = *(const h16x8*)(kvh + (size_t)g * 512 + 256 + c * 8);
    }

    float m = s[0];
    #pragma unroll
    for (int i = 1; i < 16; ++i) m = fmaxf(m, s[i]);
    m = fmaxf(m, __shfl_xor(m, 32));
    float tot = 0.0f;
    #pragma unroll
    for (int i = 0; i < 16; ++i) { s[i] = __expf(s[i] - m); tot += s[i]; }
    tot += __shfl_xor(tot, 32);
    const float inv = 1.0f / tot;

    float a[8] = {};
    #pragma unroll
    for (int i = 0; i < 16; ++i) {
        float wt = s[i] * inv;
        #pragma unroll
        for (int j = 0; j < 8; ++j) a[j] += wt * (float)vr[i][j];
    }
    #pragma unroll
    for (int j = 0; j < 8; ++j) a[j] += __shfl_xor(a[j], 32);

    if (pp == 0) {
        bf16x8 ov;
        #pragma unroll
        for (int j = 0; j < 8; ++j)
            ov[j] = __builtin_bit_cast(short, __float2bfloat16(a[j]));
        *(bf16x8*)((short*)out + (size_t)n * 256 + c * 8) = ov;
    }
}

// ---------------------------------------------------------------------------
extern "C" void kernel_launch(void* const* d_in, const int* in_sizes, int n_in,
                              void* d_out, int out_size, void* d_ws, size_t ws_size,
                              hipStream_t stream)
{
    const float* src = (const float*)d_in[0];
    const int*   index_pair = (const int*)d_in[1];
    const int*   kbc = (const int*)d_in[3];
    const int*   ipb = (const int*)d_in[4];
    const float* Wq = (const float*)d_in[5];
    const float* bq = (const float*)d_in[6];
    const float* Wk = (const float*)d_in[7];
    const float* bk = (const float*)d_in[8];
    const float* Wv = (const float*)d_in[9];
    const float* bv = (const float*)d_in[10];
    const float* Wo = (const float*)d_in[11];
    const float* bo = (const float*)d_in[12];
    const float* W1 = (const float*)d_in[13];
    const float* b1 = (const float*)d_in[14];
    const float* W2 = (const float*)d_in[15];
    const float* b2 = (const float*)d_in[16];
    const float* g1 = (const float*)d_in[17];
    const float* be1 = (const float*)d_in[18];
    const float* g2 = (const float*)d_in[19];
    const float* be2 = (const float*)d_in[20];
    float* out = (float*)d_out;
    const int nb = in_sizes[3];

    char* ws = (char*)d_ws;
    const size_t O_SRCBF = 0;                        //  8.39 MB bf16 src
    const size_t O_QH    = 8388608;                  //  8.39 MB fp16 q
    const size_t O_KVH   = 25165824;                 // 16.78 MB fp16 k|v
    const size_t O_ATTN  = 41943040;                 //  8.39 MB bf16 attn out
    const size_t O_HC    = 0;                        // 64 MB alias (FFN hidden)
    const size_t O_XBF   = 67108864;                 //  8.39 MB bf16 x (LN1 out)
    const size_t O_WQKV  = 75497472;
    const size_t O_WO    = O_WQKV + 768 * 256 * 2;
    const size_t O_W1    = O_WO + 256 * 256 * 2;
    const size_t O_W2    = O_W1 + (size_t)DFF * 256 * 2;
    const size_t O_BQKV  = O_W2 + (size_t)DFF * 256 * 2;
    const size_t O_KS    = O_BQKV + 768 * 4;

    __hip_bfloat16* src_bf  = (__hip_bfloat16*)(ws + O_SRCBF);
    _Float16*       qh      = (_Float16*)(ws + O_QH);
    _Float16*       kvh     = (_Float16*)(ws + O_KVH);
    __hip_bfloat16* attn_bf = (__hip_bfloat16*)(ws + O_ATTN);
    __hip_bfloat16* hc      = (__hip_bfloat16*)(ws + O_HC);
    __hip_bfloat16* x_bf    = (__hip_bfloat16*)(ws + O_XBF);
    __hip_bfloat16* WqkvT   = (__hip_bfloat16*)(ws + O_WQKV);
    __hip_bfloat16* WoT     = (__hip_bfloat16*)(ws + O_WO);
    __hip_bfloat16* W1T     = (__hip_bfloat16*)(ws + O_W1);
    __hip_bfloat16* W2T     = (__hip_bfloat16*)(ws + O_W2);
    float*          bqkv    = (float*)(ws + O_BQKV);
    int*            ksbuf   = (int*)(ws + O_KS);

    const dim3 blk(256);
    const float qscale = 0.17677669529663687f;

    hipFuncSetAttribute(reinterpret_cast<const void*>(gemm_bk64_ln32),
                        hipFuncAttributeMaxDynamicSharedMemorySize, SMEM_LN32);

    // --- ALL conversions in one dispatch ---
    cvt_all<<<5377, blk, 0, stream>>>(src, src_bf, Wq, Wk, Wv, Wo, W1, W2,
                                      bq, bk, bv, kbc, nb,
                                      WqkvT, WoT, W1T, W2T, bqkv, ksbuf, qscale);

    // --- fused QKV projection (flat 768-block grid, XCD-swizzled) ---
    gemm_qkv<<<768, blk, 0, stream>>>(src_bf, WqkvT, bqkv, qh, kvh);

    // --- gathered attention (wave per query, fp16 dot2) ---
    attn_wave<<<dim3(N_TOK / 4), blk, 0, stream>>>(qh, kvh, index_pair, ipb, ksbuf, attn_bf);

    // --- Wo + residual(src) + LN1 fused -> x_bf ---
    gemm_bk64_ln32<<<dim3(N_TOK / 32), dim3(512), SMEM_LN32, stream>>>(
        attn_bf, 256, WoT, 256, bo, src, nullptr, g1, be1,
        nullptr, x_bf, 256);

    // --- FFN1 (N=2048, relu) -> hc (flat 2048-block grid, XCD-swizzled) ---
    gemm_bt<<<2048, blk, 0, stream>>>(
        x_bf, 256, W1T, 256, b1, hc, DFF, N_TOK, DFF, 256, 1, 16);

    // --- FFN2 + residual(x_bf) + LN2 fused -> out ---
    gemm_bk64_ln32<<<dim3(N_TOK / 32), dim3(512), SMEM_LN32, stream>>>(
        hc, DFF, W2T, DFF, b2, nullptr, x_bf, g2, be2,
        out, nullptr, DFF);
}